// Round 20
// baseline (83.712 us; speedup 1.0000x reference)
//
#include <hip/hip_runtime.h>
#include <hip/hip_bf16.h>
#include <math.h>

#define BB 64
#define NN 64
#define HH 256
#define FF 8

typedef __bf16 bf16;
typedef bf16 bf16x2 __attribute__((ext_vector_type(2)));
typedef bf16 bf16x4 __attribute__((ext_vector_type(4)));
typedef bf16 bf16x8 __attribute__((ext_vector_type(8)));
typedef float f32x2 __attribute__((ext_vector_type(2)));
typedef float f32x4 __attribute__((ext_vector_type(4)));

// async global->LDS, 16B per lane; LDS dest = uniform base + lane*16,
// global src must be PER-LANE (carry the lane offset explicitly!)
#define GLL(g, l) __builtin_amdgcn_global_load_lds( \
    (const __attribute__((address_space(1))) void*)(g), \
    (__attribute__((address_space(3))) void*)(l), 16, 0, 0)

#define MFMA(a, b, c) __builtin_amdgcn_mfma_f32_16x16x32_bf16(a, b, c, 0, 0, 0)

// counted waits for per-wave GLL staging ("memory" clobber orders mem ops;
// no sched_barrier — R19 verified neutral-to-required-free)
#define WAITVM2 asm volatile("s_waitcnt vmcnt(2)" ::: "memory")
#define WAITVM0 asm volatile("s_waitcnt vmcnt(0)" ::: "memory")

#define LOG2E 1.44269504f
#define LN2   0.69314718f

__device__ __forceinline__ f32x2 unpk(unsigned int u) {
    union { unsigned int i; float f; } a, b;
    a.i = (u & 0xffffu) << 16;
    b.i = u & 0xffff0000u;
    f32x2 r; r.x = a.f; r.y = b.f; return r;
}

// MFMA B-fragment direct from global [N][K] bf16 (R6-proven pattern):
// elems k = base + {0..3} and base+16..19
__device__ __forceinline__ bf16x8 ldfrag(const bf16* p) {
    bf16x4 lo = *(const bf16x4*)p;
    bf16x4 hi = *(const bf16x4*)(p + 16);
    return __builtin_shufflevector(lo, hi, 0, 1, 2, 3, 4, 5, 6, 7);
}

// fragment from swizzled LDS tile with 128-B rows
__device__ __forceinline__ bf16x8 frag128(const char* base, int row, int cbyte) {
    const int sw = (row & 7) << 4;
    const int a = row * 128 + cbyte;
    bf16x4 lo = *(const bf16x4*)(base + (a ^ sw));
    bf16x4 hi = *(const bf16x4*)(base + ((a + 32) ^ sw));
    return __builtin_shufflevector(lo, hi, 0, 1, 2, 3, 4, 5, 6, 7);
}

// fragment from swizzled LDS tile with 512-B rows
__device__ __forceinline__ bf16x8 frag512(const char* base, int row, int cbyte) {
    const int sw = (row & 7) << 4;
    const int a = row * 512 + cbyte;
    bf16x4 lo = *(const bf16x4*)(base + (a ^ sw));
    bf16x4 hi = *(const bf16x4*)(base + ((a + 32) ^ sw));
    return __builtin_shufflevector(lo, hi, 0, 1, 2, 3, 4, 5, 6, 7);
}

// fragment from swizzled LDS tile with 1024-B rows
__device__ __forceinline__ bf16x8 frag1024(const char* base, int row, int cbyte) {
    const int sw = (row & 7) << 4;
    const int a = row * 1024 + cbyte;
    bf16x4 lo = *(const bf16x4*)(base + (a ^ sw));
    bf16x4 hi = *(const bf16x4*)(base + ((a + 32) ^ sw));
    return __builtin_shufflevector(lo, hi, 0, 1, 2, 3, 4, 5, 6, 7);
}

__device__ __forceinline__ void st512(char* base, int row, int col, bf16 v) {
    *(bf16*)(base + ((row * 512 + col * 2) ^ ((row & 7) << 4))) = v;
}

// ---------------------------------------------------------------------------
// G1 + pack, one dispatch (R9 proven, unchanged). Grid (16, 71).
// ---------------------------------------------------------------------------
__global__ __launch_bounds__(256) void g1pack_kernel(
    const float* __restrict__ hidden, const float* __restrict__ ed_w1,
    const float* __restrict__ ed_w2,
    const float* __restrict__ wr, const float* __restrict__ wi,
    const float* __restrict__ wh,
    const float* __restrict__ f1_w, const float* __restrict__ f2_w,
    bf16* __restrict__ PQ, bf16* __restrict__ W2t, bf16* __restrict__ Wg,
    bf16* __restrict__ f1t, bf16* __restrict__ f2t)
{
    __shared__ __align__(1024) char smem[49408];
    const int tid = threadIdx.x;

    if (blockIdx.y >= 64) {
        const int t = (blockIdx.y - 64) * 16 + blockIdx.x;
        const float* src; bf16* dst; int R, C, tile;
        if (t < 32) { src = ed_w2; dst = W2t; R = 512; C = 256; tile = t; }
        else {
            int m = (t - 32) >> 4; tile = (t - 32) & 15; R = 256; C = 256;
            const float* ss[5] = {wr, wi, wh, f1_w, f2_w};
            bf16* dd[5] = {Wg, Wg + 65536, Wg + 131072, f1t, f2t};
            src = ss[m]; dst = dd[m];
        }
        const int tc = C >> 6;
        const int k0 = (tile / tc) * 64, n0 = (tile % tc) * 64;
        float (*ls)[65] = (float(*)[65])smem;
        {
            int rr = tid >> 2, cc = (tid & 3) * 16;
            const float* sp = src + (size_t)(k0 + rr) * C + n0 + cc;
#pragma unroll
            for (int j = 0; j < 16; j += 4) {
                float4 v = *(const float4*)(sp + j);
                ls[rr][cc + j] = v.x; ls[rr][cc + j + 1] = v.y;
                ls[rr][cc + j + 2] = v.z; ls[rr][cc + j + 3] = v.w;
            }
        }
        __syncthreads();
        {
            int n = tid >> 2, kc = (tid & 3) * 16;
            bf16x8 o0, o1;
#pragma unroll
            for (int j = 0; j < 8; ++j) o0[j] = (bf16)ls[kc + j][n];
#pragma unroll
            for (int j = 0; j < 8; ++j) o1[j] = (bf16)ls[kc + 8 + j][n];
            bf16* dp = dst + (size_t)(n0 + n) * R + k0 + kc;
            *(bf16x8*)dp = o0;
            *(bf16x8*)(dp + 8) = o1;
        }
        return;
    }

    char* Bs = smem;
    char* pool = smem + 32768;
    const int wave = tid >> 6, lane = tid & 63;
    const int wr_ = wave >> 1, wc_ = wave & 1;
    const int l15 = lane & 15, l4 = lane >> 4;
    const int bm = blockIdx.y * 64, bn = blockIdx.x * 64;
    const int roff = (bn >= 512) ? 256 : 0;
    const int ncol = bn & 511;

    {
        float (*ls)[65] = (float(*)[65])pool;
#pragma unroll
        for (int kt = 0; kt < 4; ++kt) {
            {
                int rr = tid >> 2, cc = (tid & 3) * 16;
                const float* sp = ed_w1 + (size_t)(kt * 64 + roff + rr) * 512 + ncol + cc;
#pragma unroll
                for (int j = 0; j < 16; j += 4) {
                    float4 v = *(const float4*)(sp + j);
                    ls[rr][cc + j] = v.x; ls[rr][cc + j + 1] = v.y;
                    ls[rr][cc + j + 2] = v.z; ls[rr][cc + j + 3] = v.w;
                }
            }
            __syncthreads();
            {
                int n = tid >> 2, kc = (tid & 3) * 16;
                bf16x8 o0, o1;
#pragma unroll
                for (int j = 0; j < 8; ++j) o0[j] = (bf16)ls[kc + j][n];
#pragma unroll
                for (int j = 0; j < 8; ++j) o1[j] = (bf16)ls[kc + 8 + j][n];
                int cb0 = kt * 8 + (kc >> 3);
                char* rowp = Bs + n * 512;
                *(bf16x8*)(rowp + ((cb0 ^ (n & 7)) * 16)) = o0;
                *(bf16x8*)(rowp + (((cb0 + 1) ^ (n & 7)) * 16)) = o1;
            }
            __syncthreads();
        }
    }

    f32x4 acc[2][2];
#pragma unroll
    for (int mf = 0; mf < 2; ++mf)
#pragma unroll
        for (int nf = 0; nf < 2; ++nf)
            acc[mf][nf] = (f32x4){0.f, 0.f, 0.f, 0.f};

    auto stageA = [&](int buf, int kt) {
        char* Ab = pool + buf * 8192;
#pragma unroll
        for (int a = 0; a < 2; ++a) {
            int idx = a * 256 + tid;
            int row = idx >> 3, cb = idx & 7;
            const float* gp = hidden + (size_t)(bm + row) * 256 + kt * 64 + cb * 8;
            float4 v0 = *(const float4*)gp;
            float4 v1 = *(const float4*)(gp + 4);
            bf16x8 o;
            o[0] = (bf16)v0.x; o[1] = (bf16)v0.y; o[2] = (bf16)v0.z; o[3] = (bf16)v0.w;
            o[4] = (bf16)v1.x; o[5] = (bf16)v1.y; o[6] = (bf16)v1.z; o[7] = (bf16)v1.w;
            *(bf16x8*)(Ab + row * 128 + ((cb ^ (row & 7)) * 16)) = o;
        }
    };

    auto computeT = [&](int buf, int kt) {
        char* Ab = pool + buf * 8192;
#pragma unroll
        for (int kk = 0; kk < 2; ++kk) {
            bf16x8 af[2];
#pragma unroll
            for (int mf = 0; mf < 2; ++mf)
                af[mf] = frag128(Ab, wr_ * 32 + mf * 16 + l15, kk * 64 + l4 * 8);
#pragma unroll
            for (int nf = 0; nf < 2; ++nf) {
                bf16x8 bfr = frag512(Bs, wc_ * 32 + nf * 16 + l15,
                                     kt * 128 + kk * 64 + l4 * 8);
#pragma unroll
                for (int mf = 0; mf < 2; ++mf)
                    acc[mf][nf] = MFMA(af[mf], bfr, acc[mf][nf]);
            }
        }
    };

    stageA(0, 0);
    __syncthreads();
#pragma unroll
    for (int t = 0; t < 4; ++t) {
        if (t < 3) stageA((t + 1) & 1, t + 1);
        computeT(t & 1, t);
        __syncthreads();
    }

#pragma unroll
    for (int mf = 0; mf < 2; ++mf)
#pragma unroll
        for (int nf = 0; nf < 2; ++nf)
#pragma unroll
            for (int r = 0; r < 4; ++r) {
                int grow = bm + wr_ * 32 + mf * 16 + l4 * 4 + r;
                int col = bn + wc_ * 32 + nf * 16 + l15;
                PQ[(size_t)grow * 1024 + col] = (bf16)acc[mf][nf][r];
            }
}

// ---------------------------------------------------------------------------
// FUSED (R19 base + T14 register prefetch for phases 2 and 4):
//  - phase 2 B (W2t, 8 k-steps) prefetched into 64 VGPR during phase 0;
//    arrival guaranteed by the phase-0 __syncthreads (vmcnt drain).
//  - phase 4 B (f1t, 4 k-steps) prefetched into 32 VGPR at the start of
//    phase 3's VALU epilogue; drained by the phase-3 barrier.
//  - phases 3 and 5 keep GLL double-buffer staging (proven).
// Grid 256, 1024 threads (16 waves). Edge = R18-proven split-accum elu.
// LDS map (102400 B): identical to R13/R18/R19.
// ---------------------------------------------------------------------------
__global__ __launch_bounds__(1024) void fused_kernel(
    const bf16* __restrict__ PQ, const float* __restrict__ edges,
    const float* __restrict__ b1,
    const bf16* __restrict__ W2t, const float* __restrict__ ed_b2,
    const bf16* __restrict__ Wg,
    const bf16* __restrict__ f1t, const float* __restrict__ f1_b,
    const bf16* __restrict__ f2t, const float* __restrict__ f2_b,
    const float* __restrict__ f3_w, const float* __restrict__ f3_b,
    const float* __restrict__ inputs, const float* __restrict__ hidden,
    const float* __restrict__ irw, const float* __restrict__ irb,
    const float* __restrict__ iiw, const float* __restrict__ iib,
    const float* __restrict__ inw, const float* __restrict__ inb,
    float* __restrict__ NH, float* __restrict__ pred)
{
    __shared__ __align__(1024) char smem[102400];
    char* qs   = smem;
    char* sl   = smem + 65536;
    float* f3s = (float*)(smem + 65536);   // alias sl (after ph2)
    char* h1l  = smem + 73728;             // alias sl upper half (after ph2)
    char* aggl = smem + 81920;
    char* h2l  = smem + 81920;             // alias aggl (after ph3)
    char* nhl  = smem + 90112;
    float (*wls)[16] = (float(*)[16])(smem + 98304);

    const int tid = threadIdx.x;
    const int wave = tid >> 6, lane = tid & 63;
    const int l15 = lane & 15, l4 = lane >> 4;
    const int srow = lane >> 3;
    const int scol = ((lane & 7) ^ (lane >> 3)) * 8;
    // XCD-bijective swizzle: all 4 quarters of a batch on one XCD
    const int vb = (blockIdx.x & 7) * 32 + (blockIdx.x >> 3);
    const int b = vb >> 2, d0 = (vb & 3) * 16;
    const bf16* Pb = PQ + (size_t)(b * 64) * 1024;
    char* mybuf = qs + wave * 4096;        // per-wave B double-buffer (2x2KB)
    const int n0 = wave * 16;              // wave's 16 output columns

    auto stageB = [&](const bf16* Wt, int Krow, int bufi, int kt) {
        char* d = mybuf + bufi * 2048;
#pragma unroll
        for (int s = 0; s < 2; ++s)
            GLL(Wt + (size_t)(n0 + s * 8 + srow) * Krow + kt * 64 + scol,
                d + s * 1024 + lane * 16);
    };

    // ---- phase 0: stage Q (GLL), prefetch W2t frags to regs, wls, p2 ----
#pragma unroll
    for (int si = 0; si < 4; ++si) {
        int row = wave * 4 + si;
        GLL(Pb + (size_t)row * 1024 + 512 + lane * 8, qs + row * 1024 + lane * 16);
    }
    // W2t register prefetch: 16 fragments (8 kt x 2 kk), 64 VGPR.
    // Uncoalesced but issued ~entire edge-phase ahead of use; the phase-0
    // __syncthreads drains vmcnt so they are guaranteed resident.
    bf16x8 w2f[16];
    {
        const bf16* wrow = W2t + (size_t)(n0 + l15) * 512 + l4 * 4;
#pragma unroll
        for (int kt = 0; kt < 8; ++kt)
#pragma unroll
            for (int kk = 0; kk < 2; ++kk)
                w2f[kt * 2 + kk] = ldfrag(wrow + kt * 64 + kk * 32);
    }
    {
        int src = tid >> 4, dc = tid & 15, d = d0 + dc;
        float w = 0.f;
        if (src != d) {
            int e = src * 63 + (d < src ? d : d - 1);
            float2 ev = ((const float2*)edges)[e];
            w = fmaxf(ev.x, ev.y) * LOG2E;
        }
        wls[src][dc] = w;
    }
    const int c = tid & 255, hh = tid >> 8;   // hh in [0,4): 4-dst group
    f32x2 p2[4];
#pragma unroll
    for (int dd = 0; dd < 4; ++dd)
        p2[dd] = unpk(*(const unsigned int*)(Pb + (size_t)(d0 + hh * 4 + dd) * 1024 + 2 * c));
    float2 bbl = *(const float2*)(b1 + 2 * c);
    f32x2 bb;  bb.x = bbl.x;  bb.y = bbl.y;
    f32x2 bb2; bb2.x = bb.x * LOG2E; bb2.y = bb.y * LOG2E;
    __syncthreads();

    // ---- phase 1: edge elu-sum, split accumulators (exact identity) ----
    {
        f32x2 accP[4], accE[4];
#pragma unroll
        for (int dd = 0; dd < 4; ++dd) {
            accP[dd] = (f32x2){0.f, 0.f};
            accE[dd] = (f32x2){0.f, 0.f};
        }
        const unsigned int* Qs32 = (const unsigned int*)qs;
#pragma unroll 4
        for (int src = 0; src < 64; ++src) {
            f32x2 qv = unpk(Qs32[src * 256 + c]);
            float4 wv = *(const float4*)&wls[src][hh * 4];
            float w[4] = {wv.x, wv.y, wv.z, wv.w};
#pragma unroll
            for (int dd = 0; dd < 4; ++dd) {
                f32x2 w2v; w2v.x = w[dd]; w2v.y = w[dd];
                f32x2 u = (p2[dd] + qv) * w2v + bb2;
                accP[dd].x += fmaxf(u.x, 0.f);
                accP[dd].y += fmaxf(u.y, 0.f);
                accE[dd].x += __builtin_amdgcn_exp2f(fminf(u.x, 0.f));
                accE[dd].y += __builtin_amdgcn_exp2f(fminf(u.y, 0.f));
            }
        }
        f32x2 selfc;
        selfc.x = (bb.x > 0.f) ? bb.x : (__expf(bb.x) - 1.f);
        selfc.y = (bb.y > 0.f) ? bb.y : (__expf(bb.y) - 1.f);
#pragma unroll
        for (int dd = 0; dd < 4; ++dd) {
            int row = hh * 4 + dd;
            bf16x2 st;
            st[0] = (bf16)(LN2 * accP[dd].x + accE[dd].x - 64.f - selfc.x);
            st[1] = (bf16)(LN2 * accP[dd].y + accE[dd].y - 64.f - selfc.y);
            *(bf16x2*)(sl + ((row * 1024 + 4 * c) ^ ((row & 7) << 4))) = st;
        }
    }
    __syncthreads();   // Q dead -> qs becomes per-wave B buffers

    // ---- phase 2: agg = S @ W2 / 63 + b2  (K=512, B from registers) ----
    {
        f32x4 a1 = (f32x4){0.f, 0.f, 0.f, 0.f};
#pragma unroll
        for (int kt = 0; kt < 8; ++kt)
#pragma unroll
            for (int kk = 0; kk < 2; ++kk) {
                bf16x8 af = frag1024(sl, l15, kt * 128 + kk * 64 + l4 * 8);
                a1 = MFMA(af, w2f[kt * 2 + kk], a1);
            }
        int col = n0 + l15;
        float eb = ed_b2[col];
#pragma unroll
        for (int r = 0; r < 4; ++r)
            st512(aggl, l4 * 4 + r, col, (bf16)(a1[r] * (1.f / 63.f) + eb));
    }
    __syncthreads();   // sl dead -> f3s/h1l regions usable

    for (int i = tid; i < 2048; i += 1024) f3s[i] = f3_w[i];

    // ---- phase 3: gates (3 x K=256, 12 GLL-staged steps) + GRU epilogue ----
    {
        f32x4 a2[3];
#pragma unroll
        for (int g = 0; g < 3; ++g) a2[g] = (f32x4){0.f, 0.f, 0.f, 0.f};
        stageB(Wg, 256, 0, 0);
#pragma unroll
        for (int st_ = 0; st_ < 12; ++st_) {
            const int g = st_ >> 2, kt = st_ & 3;
            if (st_ < 11) {
                const int nx = st_ + 1;
                stageB(Wg + (size_t)(nx >> 2) * 65536, 256, nx & 1, nx & 3);
                WAITVM2;
            } else { WAITVM0; }
            const char* bbuf = mybuf + (st_ & 1) * 2048;
#pragma unroll
            for (int kk = 0; kk < 2; ++kk) {
                bf16x8 af = frag512(aggl, l15, kt * 128 + kk * 64 + l4 * 8);
                a2[g] = MFMA(af, frag128(bbuf, l15, kk * 64 + l4 * 8), a2[g]);
            }
        }
        // f1t register prefetch for phase 4 (8 frags, 32 VGPR), hidden under
        // the GRU epilogue's VALU; drained by the phase-3 barrier.
        bf16x8 f1f[8];
        {
            const bf16* frow = f1t + (size_t)(n0 + l15) * 256 + l4 * 4;
#pragma unroll
            for (int kt = 0; kt < 4; ++kt)
#pragma unroll
                for (int kk = 0; kk < 2; ++kk)
                    f1f[kt * 2 + kk] = ldfrag(frow + kt * 64 + kk * 32);
        }
        const int col = n0 + l15;
        float w8r[8], w8i[8], w8n[8];
#pragma unroll
        for (int f = 0; f < 8; ++f) {
            w8r[f] = irw[f * 256 + col];
            w8i[f] = iiw[f * 256 + col];
            w8n[f] = inw[f * 256 + col];
        }
        const float xr0 = irb[col], xi0 = iib[col], xn0 = inb[col];
#pragma unroll
        for (int r = 0; r < 4; ++r) {
            const int lrow = l4 * 4 + r;
            const int grow = b * 64 + d0 + lrow;
            const float* inp = inputs + (size_t)grow * 8;
            float xr = xr0, xi = xi0, xn = xn0;
#pragma unroll
            for (int f = 0; f < 8; ++f) {
                float x = inp[f];
                xr += x * w8r[f]; xi += x * w8i[f]; xn += x * w8n[f];
            }
            float aR = a2[0][r];
            float aI = a2[1][r];
            float aN = a2[2][r];
            float rg = __builtin_amdgcn_rcpf(1.f + __expf(-(xr + aR)));
            float ig = __builtin_amdgcn_rcpf(1.f + __expf(-(xi + aI)));
            float tz = xn + rg * aN;
            tz = fminf(fmaxf(tz, -15.f), 15.f);
            float e2x = __expf(2.f * tz);
            float nn = (e2x - 1.f) * __builtin_amdgcn_rcpf(e2x + 1.f);
            size_t o = (size_t)grow * 256 + col;
            float nh = (1.f - ig) * nn + ig * hidden[o];
            NH[o] = nh;
            st512(nhl, lrow, col, (bf16)nh);
        }
        __syncthreads();   // aggl dead -> h2l region usable; f1f resident

        // ---- phase 4: H1 = relu(NH @ f1 + b)  (K=256, B from registers) ----
        {
            f32x4 a1 = (f32x4){0.f, 0.f, 0.f, 0.f};
#pragma unroll
            for (int kt = 0; kt < 4; ++kt)
#pragma unroll
                for (int kk = 0; kk < 2; ++kk) {
                    bf16x8 af = frag512(nhl, l15, kt * 128 + kk * 64 + l4 * 8);
                    a1 = MFMA(af, f1f[kt * 2 + kk], a1);
                }
            float bv = f1_b[col];
#pragma unroll
            for (int r = 0; r < 4; ++r)
                st512(h1l, l4 * 4 + r, col, (bf16)fmaxf(a1[r] + bv, 0.f));
        }
    }
    __syncthreads();

    // ---- phase 5: H2 = relu(H1 @ f2 + b)  (K=256, 4 GLL-staged steps) ----
    {
        f32x4 a1 = (f32x4){0.f, 0.f, 0.f, 0.f};
        stageB(f2t, 256, 0, 0);
#pragma unroll
        for (int kt = 0; kt < 4; ++kt) {
            if (kt < 3) { stageB(f2t, 256, (kt + 1) & 1, kt + 1); WAITVM2; }
            else { WAITVM0; }
            const char* bbuf = mybuf + (kt & 1) * 2048;
#pragma unroll
            for (int kk = 0; kk < 2; ++kk) {
                bf16x8 af = frag512(h1l, l15, kt * 128 + kk * 64 + l4 * 8);
                a1 = MFMA(af, frag128(bbuf, l15, kk * 64 + l4 * 8), a1);
            }
        }
        int col = n0 + l15;
        float bv = f2_b[col];
#pragma unroll
        for (int r = 0; r < 4; ++r)
            st512(h2l, l4 * 4 + r, col, (bf16)fmaxf(a1[r] + bv, 0.f));
    }
    __syncthreads();

    // ---- phase 6: pred = inputs + H2 @ f3 + b ----
    if (tid < 128) {
        const int row = tid >> 3, f = tid & 7;
        const int sw = (row & 7) << 4;
        float a = f3_b[f];
        for (int k0 = 0; k0 < 256; k0 += 8) {
            bf16x8 h8 = *(const bf16x8*)(h2l + ((row * 512 + k0 * 2) ^ sw));
#pragma unroll
            for (int j = 0; j < 8; ++j)
                a += (float)h8[j] * f3s[(k0 + j) * 8 + f];
        }
        int gi = (b * 64 + d0 + row) * 8 + f;
        pred[gi] = inputs[gi] + a;
    }
}

// ---------------------------------------------------------------------------
extern "C" void kernel_launch(void* const* d_in, const int* in_sizes, int n_in,
                              void* d_out, int out_size, void* d_ws, size_t ws_size,
                              hipStream_t stream) {
    const float* inputs = (const float*)d_in[0];
    const float* hidden = (const float*)d_in[1];
    const float* edges  = (const float*)d_in[2];
    const float* ed_w1 = (const float*)d_in[4];
    const float* ed_b1 = (const float*)d_in[5];
    const float* ed_w2 = (const float*)d_in[6];
    const float* ed_b2 = (const float*)d_in[7];
    const float* wr = (const float*)d_in[8];
    const float* wi = (const float*)d_in[9];
    const float* wh = (const float*)d_in[10];
    const float* ir_w = (const float*)d_in[11];
    const float* ir_b = (const float*)d_in[12];
    const float* ii_w = (const float*)d_in[13];
    const float* ii_b = (const float*)d_in[14];
    const float* in_w = (const float*)d_in[15];
    const float* in_b = (const float*)d_in[16];
    const float* f1_w = (const float*)d_in[17];
    const float* f1_b = (const float*)d_in[18];
    const float* f2_w = (const float*)d_in[19];
    const float* f2_b = (const float*)d_in[20];
    const float* f3_w = (const float*)d_in[21];
    const float* f3_b = (const float*)d_in[22];

    float* out = (float*)d_out;
    float* pred = out;
    float* NH = out + (size_t)BB * NN * FF;

    bf16* bws = (bf16*)d_ws;
    bf16* PQ   = bws;              // 4096*1024
    bf16* W2t  = bws + 4194304;    // 256*512
    bf16* Wg   = bws + 4325376;    // 3*256*256
    bf16* f1t  = bws + 4521984;    // 256*256
    bf16* f2t  = bws + 4587520;    // 256*256

    g1pack_kernel<<<dim3(16, 71), dim3(256), 0, stream>>>(
        hidden, ed_w1, ed_w2, wr, wi, wh, f1_w, f2_w,
        PQ, W2t, Wg, f1t, f2t);

    fused_kernel<<<dim3(256), dim3(1024), 0, stream>>>(
        PQ, edges, ed_b1, W2t, ed_b2, Wg, f1t, f1_b, f2t, f2_b,
        f3_w, f3_b, inputs, hidden,
        ir_w, ir_b, ii_w, ii_b, in_w, in_b, NH, pred);
}

// Round 21
// 62.324 us; speedup vs baseline: 1.3432x; 1.3432x over previous
//
#include <hip/hip_runtime.h>
#include <hip/hip_bf16.h>
#include <math.h>

#define BB 64
#define NN 64
#define HH 256
#define FF 8

typedef __bf16 bf16;
typedef bf16 bf16x2 __attribute__((ext_vector_type(2)));
typedef bf16 bf16x4 __attribute__((ext_vector_type(4)));
typedef bf16 bf16x8 __attribute__((ext_vector_type(8)));
typedef float f32x2 __attribute__((ext_vector_type(2)));
typedef float f32x4 __attribute__((ext_vector_type(4)));

// async global->LDS, 16B per lane; LDS dest = uniform base + lane*16,
// global src must be PER-LANE (carry the lane offset explicitly!)
#define GLL(g, l) __builtin_amdgcn_global_load_lds( \
    (const __attribute__((address_space(1))) void*)(g), \
    (__attribute__((address_space(3))) void*)(l), 16, 0, 0)

#define MFMA(a, b, c) __builtin_amdgcn_mfma_f32_16x16x32_bf16(a, b, c, 0, 0, 0)

// counted waits for per-wave GLL staging ("memory" clobber orders mem ops)
#define WAITVM2 asm volatile("s_waitcnt vmcnt(2)" ::: "memory")
#define WAITVM0 asm volatile("s_waitcnt vmcnt(0)" ::: "memory")

#define LOG2E 1.44269504f
#define LN2   0.69314718f

__device__ __forceinline__ f32x2 unpk(unsigned int u) {
    union { unsigned int i; float f; } a, b;
    a.i = (u & 0xffffu) << 16;
    b.i = u & 0xffff0000u;
    f32x2 r; r.x = a.f; r.y = b.f; return r;
}

// fragment from swizzled LDS tile with 128-B rows
__device__ __forceinline__ bf16x8 frag128(const char* base, int row, int cbyte) {
    const int sw = (row & 7) << 4;
    const int a = row * 128 + cbyte;
    bf16x4 lo = *(const bf16x4*)(base + (a ^ sw));
    bf16x4 hi = *(const bf16x4*)(base + ((a + 32) ^ sw));
    return __builtin_shufflevector(lo, hi, 0, 1, 2, 3, 4, 5, 6, 7);
}

// fragment from swizzled LDS tile with 512-B rows
__device__ __forceinline__ bf16x8 frag512(const char* base, int row, int cbyte) {
    const int sw = (row & 7) << 4;
    const int a = row * 512 + cbyte;
    bf16x4 lo = *(const bf16x4*)(base + (a ^ sw));
    bf16x4 hi = *(const bf16x4*)(base + ((a + 32) ^ sw));
    return __builtin_shufflevector(lo, hi, 0, 1, 2, 3, 4, 5, 6, 7);
}

// fragment from swizzled LDS tile with 1024-B rows
__device__ __forceinline__ bf16x8 frag1024(const char* base, int row, int cbyte) {
    const int sw = (row & 7) << 4;
    const int a = row * 1024 + cbyte;
    bf16x4 lo = *(const bf16x4*)(base + (a ^ sw));
    bf16x4 hi = *(const bf16x4*)(base + ((a + 32) ^ sw));
    return __builtin_shufflevector(lo, hi, 0, 1, 2, 3, 4, 5, 6, 7);
}

__device__ __forceinline__ void st512(char* base, int row, int col, bf16 v) {
    *(bf16*)(base + ((row * 512 + col * 2) ^ ((row & 7) << 4))) = v;
}

// ---------------------------------------------------------------------------
// G1 + pack, one dispatch (R9 proven, unchanged). Grid (16, 71).
// ---------------------------------------------------------------------------
__global__ __launch_bounds__(256) void g1pack_kernel(
    const float* __restrict__ hidden, const float* __restrict__ ed_w1,
    const float* __restrict__ ed_w2,
    const float* __restrict__ wr, const float* __restrict__ wi,
    const float* __restrict__ wh,
    const float* __restrict__ f1_w, const float* __restrict__ f2_w,
    bf16* __restrict__ PQ, bf16* __restrict__ W2t, bf16* __restrict__ Wg,
    bf16* __restrict__ f1t, bf16* __restrict__ f2t)
{
    __shared__ __align__(1024) char smem[49408];
    const int tid = threadIdx.x;

    if (blockIdx.y >= 64) {
        const int t = (blockIdx.y - 64) * 16 + blockIdx.x;
        const float* src; bf16* dst; int R, C, tile;
        if (t < 32) { src = ed_w2; dst = W2t; R = 512; C = 256; tile = t; }
        else {
            int m = (t - 32) >> 4; tile = (t - 32) & 15; R = 256; C = 256;
            const float* ss[5] = {wr, wi, wh, f1_w, f2_w};
            bf16* dd[5] = {Wg, Wg + 65536, Wg + 131072, f1t, f2t};
            src = ss[m]; dst = dd[m];
        }
        const int tc = C >> 6;
        const int k0 = (tile / tc) * 64, n0 = (tile % tc) * 64;
        float (*ls)[65] = (float(*)[65])smem;
        {
            int rr = tid >> 2, cc = (tid & 3) * 16;
            const float* sp = src + (size_t)(k0 + rr) * C + n0 + cc;
#pragma unroll
            for (int j = 0; j < 16; j += 4) {
                float4 v = *(const float4*)(sp + j);
                ls[rr][cc + j] = v.x; ls[rr][cc + j + 1] = v.y;
                ls[rr][cc + j + 2] = v.z; ls[rr][cc + j + 3] = v.w;
            }
        }
        __syncthreads();
        {
            int n = tid >> 2, kc = (tid & 3) * 16;
            bf16x8 o0, o1;
#pragma unroll
            for (int j = 0; j < 8; ++j) o0[j] = (bf16)ls[kc + j][n];
#pragma unroll
            for (int j = 0; j < 8; ++j) o1[j] = (bf16)ls[kc + 8 + j][n];
            bf16* dp = dst + (size_t)(n0 + n) * R + k0 + kc;
            *(bf16x8*)dp = o0;
            *(bf16x8*)(dp + 8) = o1;
        }
        return;
    }

    char* Bs = smem;
    char* pool = smem + 32768;
    const int wave = tid >> 6, lane = tid & 63;
    const int wr_ = wave >> 1, wc_ = wave & 1;
    const int l15 = lane & 15, l4 = lane >> 4;
    const int bm = blockIdx.y * 64, bn = blockIdx.x * 64;
    const int roff = (bn >= 512) ? 256 : 0;
    const int ncol = bn & 511;

    {
        float (*ls)[65] = (float(*)[65])pool;
#pragma unroll
        for (int kt = 0; kt < 4; ++kt) {
            {
                int rr = tid >> 2, cc = (tid & 3) * 16;
                const float* sp = ed_w1 + (size_t)(kt * 64 + roff + rr) * 512 + ncol + cc;
#pragma unroll
                for (int j = 0; j < 16; j += 4) {
                    float4 v = *(const float4*)(sp + j);
                    ls[rr][cc + j] = v.x; ls[rr][cc + j + 1] = v.y;
                    ls[rr][cc + j + 2] = v.z; ls[rr][cc + j + 3] = v.w;
                }
            }
            __syncthreads();
            {
                int n = tid >> 2, kc = (tid & 3) * 16;
                bf16x8 o0, o1;
#pragma unroll
                for (int j = 0; j < 8; ++j) o0[j] = (bf16)ls[kc + j][n];
#pragma unroll
                for (int j = 0; j < 8; ++j) o1[j] = (bf16)ls[kc + 8 + j][n];
                int cb0 = kt * 8 + (kc >> 3);
                char* rowp = Bs + n * 512;
                *(bf16x8*)(rowp + ((cb0 ^ (n & 7)) * 16)) = o0;
                *(bf16x8*)(rowp + (((cb0 + 1) ^ (n & 7)) * 16)) = o1;
            }
            __syncthreads();
        }
    }

    f32x4 acc[2][2];
#pragma unroll
    for (int mf = 0; mf < 2; ++mf)
#pragma unroll
        for (int nf = 0; nf < 2; ++nf)
            acc[mf][nf] = (f32x4){0.f, 0.f, 0.f, 0.f};

    auto stageA = [&](int buf, int kt) {
        char* Ab = pool + buf * 8192;
#pragma unroll
        for (int a = 0; a < 2; ++a) {
            int idx = a * 256 + tid;
            int row = idx >> 3, cb = idx & 7;
            const float* gp = hidden + (size_t)(bm + row) * 256 + kt * 64 + cb * 8;
            float4 v0 = *(const float4*)gp;
            float4 v1 = *(const float4*)(gp + 4);
            bf16x8 o;
            o[0] = (bf16)v0.x; o[1] = (bf16)v0.y; o[2] = (bf16)v0.z; o[3] = (bf16)v0.w;
            o[4] = (bf16)v1.x; o[5] = (bf16)v1.y; o[6] = (bf16)v1.z; o[7] = (bf16)v1.w;
            *(bf16x8*)(Ab + row * 128 + ((cb ^ (row & 7)) * 16)) = o;
        }
    };

    auto computeT = [&](int buf, int kt) {
        char* Ab = pool + buf * 8192;
#pragma unroll
        for (int kk = 0; kk < 2; ++kk) {
            bf16x8 af[2];
#pragma unroll
            for (int mf = 0; mf < 2; ++mf)
                af[mf] = frag128(Ab, wr_ * 32 + mf * 16 + l15, kk * 64 + l4 * 8);
#pragma unroll
            for (int nf = 0; nf < 2; ++nf) {
                bf16x8 bfr = frag512(Bs, wc_ * 32 + nf * 16 + l15,
                                     kt * 128 + kk * 64 + l4 * 8);
#pragma unroll
                for (int mf = 0; mf < 2; ++mf)
                    acc[mf][nf] = MFMA(af[mf], bfr, acc[mf][nf]);
            }
        }
    };

    stageA(0, 0);
    __syncthreads();
#pragma unroll
    for (int t = 0; t < 4; ++t) {
        if (t < 3) stageA((t + 1) & 1, t + 1);
        computeT(t & 1, t);
        __syncthreads();
    }

#pragma unroll
    for (int mf = 0; mf < 2; ++mf)
#pragma unroll
        for (int nf = 0; nf < 2; ++nf)
#pragma unroll
            for (int r = 0; r < 4; ++r) {
                int grow = bm + wr_ * 32 + mf * 16 + l4 * 4 + r;
                int col = bn + wc_ * 32 + nf * 16 + l15;
                PQ[(size_t)grow * 1024 + col] = (bf16)acc[mf][nf][r];
            }
}

// ---------------------------------------------------------------------------
// FUSED (R19 proven, verbatim): edge split-accum elu + GLL-staged GEMM
// phases with counted vmcnt waits. Grid 256, 1024 threads (16 waves).
// XCD-bijective swizzle. LDS map (102400 B): identical to R13/R18/R19.
// ---------------------------------------------------------------------------
__global__ __launch_bounds__(1024) void fused_kernel(
    const bf16* __restrict__ PQ, const float* __restrict__ edges,
    const float* __restrict__ b1,
    const bf16* __restrict__ W2t, const float* __restrict__ ed_b2,
    const bf16* __restrict__ Wg,
    const bf16* __restrict__ f1t, const float* __restrict__ f1_b,
    const bf16* __restrict__ f2t, const float* __restrict__ f2_b,
    const float* __restrict__ f3_w, const float* __restrict__ f3_b,
    const float* __restrict__ inputs, const float* __restrict__ hidden,
    const float* __restrict__ irw, const float* __restrict__ irb,
    const float* __restrict__ iiw, const float* __restrict__ iib,
    const float* __restrict__ inw, const float* __restrict__ inb,
    float* __restrict__ NH, float* __restrict__ pred)
{
    __shared__ __align__(1024) char smem[102400];
    char* qs   = smem;
    char* sl   = smem + 65536;
    float* f3s = (float*)(smem + 65536);   // alias sl (after ph2)
    char* h1l  = smem + 73728;             // alias sl upper half (after ph2)
    char* aggl = smem + 81920;
    char* h2l  = smem + 81920;             // alias aggl (after ph3)
    char* nhl  = smem + 90112;
    float (*wls)[16] = (float(*)[16])(smem + 98304);

    const int tid = threadIdx.x;
    const int wave = tid >> 6, lane = tid & 63;
    const int l15 = lane & 15, l4 = lane >> 4;
    const int srow = lane >> 3;
    const int scol = ((lane & 7) ^ (lane >> 3)) * 8;
    // XCD-bijective swizzle: all 4 quarters of a batch on one XCD
    const int vb = (blockIdx.x & 7) * 32 + (blockIdx.x >> 3);
    const int b = vb >> 2, d0 = (vb & 3) * 16;
    const bf16* Pb = PQ + (size_t)(b * 64) * 1024;
    char* mybuf = qs + wave * 4096;        // per-wave B double-buffer (2x2KB)
    const int n0 = wave * 16;              // wave's 16 output columns

    auto stageB = [&](const bf16* Wt, int Krow, int bufi, int kt) {
        char* d = mybuf + bufi * 2048;
#pragma unroll
        for (int s = 0; s < 2; ++s)
            GLL(Wt + (size_t)(n0 + s * 8 + srow) * Krow + kt * 64 + scol,
                d + s * 1024 + lane * 16);
    };

    // ---- phase 0: stage Q (GLL, per-lane src), wls (w*log2e), p2, bb ----
#pragma unroll
    for (int si = 0; si < 4; ++si) {
        int row = wave * 4 + si;
        GLL(Pb + (size_t)row * 1024 + 512 + lane * 8, qs + row * 1024 + lane * 16);
    }
    {
        int src = tid >> 4, dc = tid & 15, d = d0 + dc;
        float w = 0.f;
        if (src != d) {
            int e = src * 63 + (d < src ? d : d - 1);
            float2 ev = ((const float2*)edges)[e];
            w = fmaxf(ev.x, ev.y) * LOG2E;
        }
        wls[src][dc] = w;
    }
    const int c = tid & 255, hh = tid >> 8;   // hh in [0,4): 4-dst group
    f32x2 p2[4];
#pragma unroll
    for (int dd = 0; dd < 4; ++dd)
        p2[dd] = unpk(*(const unsigned int*)(Pb + (size_t)(d0 + hh * 4 + dd) * 1024 + 2 * c));
    float2 bbl = *(const float2*)(b1 + 2 * c);
    f32x2 bb;  bb.x = bbl.x;  bb.y = bbl.y;
    f32x2 bb2; bb2.x = bb.x * LOG2E; bb2.y = bb.y * LOG2E;
    __syncthreads();

    // ---- phase 1: edge elu-sum, split accumulators (exact identity) ----
    {
        f32x2 accP[4], accE[4];
#pragma unroll
        for (int dd = 0; dd < 4; ++dd) {
            accP[dd] = (f32x2){0.f, 0.f};
            accE[dd] = (f32x2){0.f, 0.f};
        }
        const unsigned int* Qs32 = (const unsigned int*)qs;
#pragma unroll 4
        for (int src = 0; src < 64; ++src) {
            f32x2 qv = unpk(Qs32[src * 256 + c]);
            float4 wv = *(const float4*)&wls[src][hh * 4];
            float w[4] = {wv.x, wv.y, wv.z, wv.w};
#pragma unroll
            for (int dd = 0; dd < 4; ++dd) {
                f32x2 w2v; w2v.x = w[dd]; w2v.y = w[dd];
                f32x2 u = (p2[dd] + qv) * w2v + bb2;
                accP[dd].x += fmaxf(u.x, 0.f);
                accP[dd].y += fmaxf(u.y, 0.f);
                accE[dd].x += __builtin_amdgcn_exp2f(fminf(u.x, 0.f));
                accE[dd].y += __builtin_amdgcn_exp2f(fminf(u.y, 0.f));
            }
        }
        f32x2 selfc;
        selfc.x = (bb.x > 0.f) ? bb.x : (__expf(bb.x) - 1.f);
        selfc.y = (bb.y > 0.f) ? bb.y : (__expf(bb.y) - 1.f);
#pragma unroll
        for (int dd = 0; dd < 4; ++dd) {
            int row = hh * 4 + dd;
            bf16x2 st;
            st[0] = (bf16)(LN2 * accP[dd].x + accE[dd].x - 64.f - selfc.x);
            st[1] = (bf16)(LN2 * accP[dd].y + accE[dd].y - 64.f - selfc.y);
            *(bf16x2*)(sl + ((row * 1024 + 4 * c) ^ ((row & 7) << 4))) = st;
        }
    }
    __syncthreads();   // Q dead -> qs becomes per-wave B buffers

    // ---- phase 2: agg = S @ W2 / 63 + b2  (K=512, 8 staged k-steps) ----
    {
        f32x4 a1 = (f32x4){0.f, 0.f, 0.f, 0.f};
        stageB(W2t, 512, 0, 0);
#pragma unroll
        for (int kt = 0; kt < 8; ++kt) {
            if (kt < 7) { stageB(W2t, 512, (kt + 1) & 1, kt + 1); WAITVM2; }
            else { WAITVM0; }
            const char* bbuf = mybuf + (kt & 1) * 2048;
#pragma unroll
            for (int kk = 0; kk < 2; ++kk) {
                bf16x8 af = frag1024(sl, l15, kt * 128 + kk * 64 + l4 * 8);
                a1 = MFMA(af, frag128(bbuf, l15, kk * 64 + l4 * 8), a1);
            }
        }
        int col = n0 + l15;
        float eb = ed_b2[col];
#pragma unroll
        for (int r = 0; r < 4; ++r)
            st512(aggl, l4 * 4 + r, col, (bf16)(a1[r] * (1.f / 63.f) + eb));
    }
    __syncthreads();   // sl dead -> f3s/h1l regions usable

    for (int i = tid; i < 2048; i += 1024) f3s[i] = f3_w[i];

    // ---- phase 3: gates (3 x K=256, 12 staged steps) + GRU epilogue ----
    {
        f32x4 a2[3];
#pragma unroll
        for (int g = 0; g < 3; ++g) a2[g] = (f32x4){0.f, 0.f, 0.f, 0.f};
        stageB(Wg, 256, 0, 0);
#pragma unroll
        for (int st_ = 0; st_ < 12; ++st_) {
            const int g = st_ >> 2, kt = st_ & 3;
            if (st_ < 11) {
                const int nx = st_ + 1;
                stageB(Wg + (size_t)(nx >> 2) * 65536, 256, nx & 1, nx & 3);
                WAITVM2;
            } else { WAITVM0; }
            const char* bbuf = mybuf + (st_ & 1) * 2048;
#pragma unroll
            for (int kk = 0; kk < 2; ++kk) {
                bf16x8 af = frag512(aggl, l15, kt * 128 + kk * 64 + l4 * 8);
                a2[g] = MFMA(af, frag128(bbuf, l15, kk * 64 + l4 * 8), a2[g]);
            }
        }
        const int col = n0 + l15;
        float w8r[8], w8i[8], w8n[8];
#pragma unroll
        for (int f = 0; f < 8; ++f) {
            w8r[f] = irw[f * 256 + col];
            w8i[f] = iiw[f * 256 + col];
            w8n[f] = inw[f * 256 + col];
        }
        const float xr0 = irb[col], xi0 = iib[col], xn0 = inb[col];
#pragma unroll
        for (int r = 0; r < 4; ++r) {
            const int lrow = l4 * 4 + r;
            const int grow = b * 64 + d0 + lrow;
            const float* inp = inputs + (size_t)grow * 8;
            float xr = xr0, xi = xi0, xn = xn0;
#pragma unroll
            for (int f = 0; f < 8; ++f) {
                float x = inp[f];
                xr += x * w8r[f]; xi += x * w8i[f]; xn += x * w8n[f];
            }
            float aR = a2[0][r];
            float aI = a2[1][r];
            float aN = a2[2][r];
            float rg = __builtin_amdgcn_rcpf(1.f + __expf(-(xr + aR)));
            float ig = __builtin_amdgcn_rcpf(1.f + __expf(-(xi + aI)));
            float tz = xn + rg * aN;
            tz = fminf(fmaxf(tz, -15.f), 15.f);
            float e2x = __expf(2.f * tz);
            float nn = (e2x - 1.f) * __builtin_amdgcn_rcpf(e2x + 1.f);
            size_t o = (size_t)grow * 256 + col;
            float nh = (1.f - ig) * nn + ig * hidden[o];
            NH[o] = nh;
            st512(nhl, lrow, col, (bf16)nh);
        }
    }
    __syncthreads();   // aggl dead -> h2l region usable

    // ---- phase 4: H1 = relu(NH @ f1 + b)  (K=256, 4 staged steps) ----
    {
        f32x4 a1 = (f32x4){0.f, 0.f, 0.f, 0.f};
        stageB(f1t, 256, 0, 0);
#pragma unroll
        for (int kt = 0; kt < 4; ++kt) {
            if (kt < 3) { stageB(f1t, 256, (kt + 1) & 1, kt + 1); WAITVM2; }
            else { WAITVM0; }
            const char* bbuf = mybuf + (kt & 1) * 2048;
#pragma unroll
            for (int kk = 0; kk < 2; ++kk) {
                bf16x8 af = frag512(nhl, l15, kt * 128 + kk * 64 + l4 * 8);
                a1 = MFMA(af, frag128(bbuf, l15, kk * 64 + l4 * 8), a1);
            }
        }
        int col = n0 + l15;
        float bv = f1_b[col];
#pragma unroll
        for (int r = 0; r < 4; ++r)
            st512(h1l, l4 * 4 + r, col, (bf16)fmaxf(a1[r] + bv, 0.f));
    }
    __syncthreads();

    // ---- phase 5: H2 = relu(H1 @ f2 + b)  (K=256, 4 staged steps) ----
    {
        f32x4 a1 = (f32x4){0.f, 0.f, 0.f, 0.f};
        stageB(f2t, 256, 0, 0);
#pragma unroll
        for (int kt = 0; kt < 4; ++kt) {
            if (kt < 3) { stageB(f2t, 256, (kt + 1) & 1, kt + 1); WAITVM2; }
            else { WAITVM0; }
            const char* bbuf = mybuf + (kt & 1) * 2048;
#pragma unroll
            for (int kk = 0; kk < 2; ++kk) {
                bf16x8 af = frag512(h1l, l15, kt * 128 + kk * 64 + l4 * 8);
                a1 = MFMA(af, frag128(bbuf, l15, kk * 64 + l4 * 8), a1);
            }
        }
        int col = n0 + l15;
        float bv = f2_b[col];
#pragma unroll
        for (int r = 0; r < 4; ++r)
            st512(h2l, l4 * 4 + r, col, (bf16)fmaxf(a1[r] + bv, 0.f));
    }
    __syncthreads();

    // ---- phase 6: pred = inputs + H2 @ f3 + b ----
    if (tid < 128) {
        const int row = tid >> 3, f = tid & 7;
        const int sw = (row & 7) << 4;
        float a = f3_b[f];
        for (int k0 = 0; k0 < 256; k0 += 8) {
            bf16x8 h8 = *(const bf16x8*)(h2l + ((row * 512 + k0 * 2) ^ sw));
#pragma unroll
            for (int j = 0; j < 8; ++j)
                a += (float)h8[j] * f3s[(k0 + j) * 8 + f];
        }
        int gi = (b * 64 + d0 + row) * 8 + f;
        pred[gi] = inputs[gi] + a;
    }
}

// ---------------------------------------------------------------------------
extern "C" void kernel_launch(void* const* d_in, const int* in_sizes, int n_in,
                              void* d_out, int out_size, void* d_ws, size_t ws_size,
                              hipStream_t stream) {
    const float* inputs = (const float*)d_in[0];
    const float* hidden = (const float*)d_in[1];
    const float* edges  = (const float*)d_in[2];
    const float* ed_w1 = (const float*)d_in[4];
    const float* ed_b1 = (const float*)d_in[5];
    const float* ed_w2 = (const float*)d_in[6];
    const float* ed_b2 = (const float*)d_in[7];
    const float* wr = (const float*)d_in[8];
    const float* wi = (const float*)d_in[9];
    const float* wh = (const float*)d_in[10];
    const float* ir_w = (const float*)d_in[11];
    const float* ir_b = (const float*)d_in[12];
    const float* ii_w = (const float*)d_in[13];
    const float* ii_b = (const float*)d_in[14];
    const float* in_w = (const float*)d_in[15];
    const float* in_b = (const float*)d_in[16];
    const float* f1_w = (const float*)d_in[17];
    const float* f1_b = (const float*)d_in[18];
    const float* f2_w = (const float*)d_in[19];
    const float* f2_b = (const float*)d_in[20];
    const float* f3_w = (const float*)d_in[21];
    const float* f3_b = (const float*)d_in[22];

    float* out = (float*)d_out;
    float* pred = out;
    float* NH = out + (size_t)BB * NN * FF;

    bf16* bws = (bf16*)d_ws;
    bf16* PQ   = bws;              // 4096*1024
    bf16* W2t  = bws + 4194304;    // 256*512
    bf16* Wg   = bws + 4325376;    // 3*256*256
    bf16* f1t  = bws + 4521984;    // 256*256
    bf16* f2t  = bws + 4587520;    // 256*256

    g1pack_kernel<<<dim3(16, 71), dim3(256), 0, stream>>>(
        hidden, ed_w1, ed_w2, wr, wi, wh, f1_w, f2_w,
        PQ, W2t, Wg, f1t, f2t);

    fused_kernel<<<dim3(256), dim3(1024), 0, stream>>>(
        PQ, edges, ed_b1, W2t, ed_b2, Wg, f1t, f1_b, f2t, f2_b,
        f3_w, f3_b, inputs, hidden,
        ir_w, ir_b, ii_w, ii_b, in_w, in_b, NH, pred);
}

// Round 22
// 60.537 us; speedup vs baseline: 1.3828x; 1.0295x over previous
//
#include <hip/hip_runtime.h>
#include <hip/hip_bf16.h>
#include <math.h>

#define BB 64
#define NN 64
#define HH 256
#define FF 8

typedef __bf16 bf16;
typedef bf16 bf16x2 __attribute__((ext_vector_type(2)));
typedef bf16 bf16x4 __attribute__((ext_vector_type(4)));
typedef bf16 bf16x8 __attribute__((ext_vector_type(8)));
typedef float f32x2 __attribute__((ext_vector_type(2)));
typedef float f32x4 __attribute__((ext_vector_type(4)));

// async global->LDS, 16B per lane; LDS dest = uniform base + lane*16,
// global src must be PER-LANE (carry the lane offset explicitly!)
#define GLL(g, l) __builtin_amdgcn_global_load_lds( \
    (const __attribute__((address_space(1))) void*)(g), \
    (__attribute__((address_space(3))) void*)(l), 16, 0, 0)

#define MFMA(a, b, c) __builtin_amdgcn_mfma_f32_16x16x32_bf16(a, b, c, 0, 0, 0)

// counted waits for per-wave GLL staging ("memory" clobber orders mem ops)
#define WAITVM2 asm volatile("s_waitcnt vmcnt(2)" ::: "memory")
#define WAITVM0 asm volatile("s_waitcnt vmcnt(0)" ::: "memory")

#define LOG2E 1.44269504f
#define LN2   0.69314718f

__device__ __forceinline__ f32x2 unpk(unsigned int u) {
    union { unsigned int i; float f; } a, b;
    a.i = (u & 0xffffu) << 16;
    b.i = u & 0xffff0000u;
    f32x2 r; r.x = a.f; r.y = b.f; return r;
}

// fragment from swizzled LDS tile with 128-B rows
__device__ __forceinline__ bf16x8 frag128(const char* base, int row, int cbyte) {
    const int sw = (row & 7) << 4;
    const int a = row * 128 + cbyte;
    bf16x4 lo = *(const bf16x4*)(base + (a ^ sw));
    bf16x4 hi = *(const bf16x4*)(base + ((a + 32) ^ sw));
    return __builtin_shufflevector(lo, hi, 0, 1, 2, 3, 4, 5, 6, 7);
}

// fragment from swizzled LDS tile with 512-B rows
__device__ __forceinline__ bf16x8 frag512(const char* base, int row, int cbyte) {
    const int sw = (row & 7) << 4;
    const int a = row * 512 + cbyte;
    bf16x4 lo = *(const bf16x4*)(base + (a ^ sw));
    bf16x4 hi = *(const bf16x4*)(base + ((a + 32) ^ sw));
    return __builtin_shufflevector(lo, hi, 0, 1, 2, 3, 4, 5, 6, 7);
}

// fragment from swizzled LDS tile with 1024-B rows
__device__ __forceinline__ bf16x8 frag1024(const char* base, int row, int cbyte) {
    const int sw = (row & 7) << 4;
    const int a = row * 1024 + cbyte;
    bf16x4 lo = *(const bf16x4*)(base + (a ^ sw));
    bf16x4 hi = *(const bf16x4*)(base + ((a + 32) ^ sw));
    return __builtin_shufflevector(lo, hi, 0, 1, 2, 3, 4, 5, 6, 7);
}

__device__ __forceinline__ void st512(char* base, int row, int col, bf16 v) {
    *(bf16*)(base + ((row * 512 + col * 2) ^ ((row & 7) << 4))) = v;
}

// ---------------------------------------------------------------------------
// G1 + pack, one dispatch. Grid (16, 39):
//   y in [0,32): G1 tile (bm=y*128, bn=x*64): PQ = bf16(hidden@[W1top|W1bot])
//     128-ROW tiles (R22): halves the per-column-redundant B transposes and
//     doubles MFMA amortization vs the R9 64-row version. Per-output ops
//     identical -> PQ bitwise unchanged.
//   y in [32,39): pack blocks t=(y-32)*16+x in [0,112):
//     t<32: ed_w2 -> W2t; else wr,wi,wh,f1_w,f2_w -> Wg/f1t/f2t.
// LDS 64 KB: Bs[64][512B] swz @0 (32K) | pool @32K (transpose ls 16.6K /
// A dbuf 2x16K).
// ---------------------------------------------------------------------------
__global__ __launch_bounds__(256) void g1pack_kernel(
    const float* __restrict__ hidden, const float* __restrict__ ed_w1,
    const float* __restrict__ ed_w2,
    const float* __restrict__ wr, const float* __restrict__ wi,
    const float* __restrict__ wh,
    const float* __restrict__ f1_w, const float* __restrict__ f2_w,
    bf16* __restrict__ PQ, bf16* __restrict__ W2t, bf16* __restrict__ Wg,
    bf16* __restrict__ f1t, bf16* __restrict__ f2t)
{
    __shared__ __align__(1024) char smem[65536];
    const int tid = threadIdx.x;

    if (blockIdx.y >= 32) {
        // ---- pack branch (R9-proven, threshold rebased) ----
        const int t = (blockIdx.y - 32) * 16 + blockIdx.x;
        const float* src; bf16* dst; int R, C, tile;
        if (t < 32) { src = ed_w2; dst = W2t; R = 512; C = 256; tile = t; }
        else {
            int m = (t - 32) >> 4; tile = (t - 32) & 15; R = 256; C = 256;
            const float* ss[5] = {wr, wi, wh, f1_w, f2_w};
            bf16* dd[5] = {Wg, Wg + 65536, Wg + 131072, f1t, f2t};
            src = ss[m]; dst = dd[m];
        }
        const int tc = C >> 6;
        const int k0 = (tile / tc) * 64, n0 = (tile % tc) * 64;
        float (*ls)[65] = (float(*)[65])smem;
        {
            int rr = tid >> 2, cc = (tid & 3) * 16;
            const float* sp = src + (size_t)(k0 + rr) * C + n0 + cc;
#pragma unroll
            for (int j = 0; j < 16; j += 4) {
                float4 v = *(const float4*)(sp + j);
                ls[rr][cc + j] = v.x; ls[rr][cc + j + 1] = v.y;
                ls[rr][cc + j + 2] = v.z; ls[rr][cc + j + 3] = v.w;
            }
        }
        __syncthreads();
        {
            int n = tid >> 2, kc = (tid & 3) * 16;
            bf16x8 o0, o1;
#pragma unroll
            for (int j = 0; j < 8; ++j) o0[j] = (bf16)ls[kc + j][n];
#pragma unroll
            for (int j = 0; j < 8; ++j) o1[j] = (bf16)ls[kc + 8 + j][n];
            bf16* dp = dst + (size_t)(n0 + n) * R + k0 + kc;
            *(bf16x8*)dp = o0;
            *(bf16x8*)(dp + 8) = o1;
        }
        return;
    }

    // ---- G1 branch: 128-row tile ----
    char* Bs = smem;
    char* pool = smem + 32768;
    const int wave = tid >> 6, lane = tid & 63;
    const int wr_ = wave >> 1, wc_ = wave & 1;
    const int l15 = lane & 15, l4 = lane >> 4;
    const int bm = blockIdx.y * 128, bn = blockIdx.x * 64;
    const int roff = (bn >= 512) ? 256 : 0;
    const int ncol = bn & 511;

    // prologue: B = transpose+cvt of ed_w1 block into swizzled Bs (unchanged)
    {
        float (*ls)[65] = (float(*)[65])pool;
#pragma unroll
        for (int kt = 0; kt < 4; ++kt) {
            {
                int rr = tid >> 2, cc = (tid & 3) * 16;
                const float* sp = ed_w1 + (size_t)(kt * 64 + roff + rr) * 512 + ncol + cc;
#pragma unroll
                for (int j = 0; j < 16; j += 4) {
                    float4 v = *(const float4*)(sp + j);
                    ls[rr][cc + j] = v.x; ls[rr][cc + j + 1] = v.y;
                    ls[rr][cc + j + 2] = v.z; ls[rr][cc + j + 3] = v.w;
                }
            }
            __syncthreads();
            {
                int n = tid >> 2, kc = (tid & 3) * 16;
                bf16x8 o0, o1;
#pragma unroll
                for (int j = 0; j < 8; ++j) o0[j] = (bf16)ls[kc + j][n];
#pragma unroll
                for (int j = 0; j < 8; ++j) o1[j] = (bf16)ls[kc + 8 + j][n];
                int cb0 = kt * 8 + (kc >> 3);
                char* rowp = Bs + n * 512;
                *(bf16x8*)(rowp + ((cb0 ^ (n & 7)) * 16)) = o0;
                *(bf16x8*)(rowp + (((cb0 + 1) ^ (n & 7)) * 16)) = o1;
            }
            __syncthreads();
        }
    }

    f32x4 acc[4][2];
#pragma unroll
    for (int mf = 0; mf < 4; ++mf)
#pragma unroll
        for (int nf = 0; nf < 2; ++nf)
            acc[mf][nf] = (f32x4){0.f, 0.f, 0.f, 0.f};

    // A staging: 128 rows x 64 cols bf16 per kt (16 KB), dbuf
    auto stageA = [&](int buf, int kt) {
        char* Ab = pool + buf * 16384;
#pragma unroll
        for (int a = 0; a < 4; ++a) {
            int idx = a * 256 + tid;
            int row = idx >> 3, cb = idx & 7;
            const float* gp = hidden + (size_t)(bm + row) * 256 + kt * 64 + cb * 8;
            float4 v0 = *(const float4*)gp;
            float4 v1 = *(const float4*)(gp + 4);
            bf16x8 o;
            o[0] = (bf16)v0.x; o[1] = (bf16)v0.y; o[2] = (bf16)v0.z; o[3] = (bf16)v0.w;
            o[4] = (bf16)v1.x; o[5] = (bf16)v1.y; o[6] = (bf16)v1.z; o[7] = (bf16)v1.w;
            *(bf16x8*)(Ab + row * 128 + ((cb ^ (row & 7)) * 16)) = o;
        }
    };

    auto computeT = [&](int buf, int kt) {
        char* Ab = pool + buf * 16384;
#pragma unroll
        for (int kk = 0; kk < 2; ++kk) {
            bf16x8 af[4];
#pragma unroll
            for (int mf = 0; mf < 4; ++mf)
                af[mf] = frag128(Ab, wr_ * 64 + mf * 16 + l15, kk * 64 + l4 * 8);
#pragma unroll
            for (int nf = 0; nf < 2; ++nf) {
                bf16x8 bfr = frag512(Bs, wc_ * 32 + nf * 16 + l15,
                                     kt * 128 + kk * 64 + l4 * 8);
#pragma unroll
                for (int mf = 0; mf < 4; ++mf)
                    acc[mf][nf] = MFMA(af[mf], bfr, acc[mf][nf]);
            }
        }
    };

    stageA(0, 0);
    __syncthreads();
#pragma unroll
    for (int t = 0; t < 4; ++t) {
        if (t < 3) stageA((t + 1) & 1, t + 1);
        computeT(t & 1, t);
        __syncthreads();
    }

#pragma unroll
    for (int mf = 0; mf < 4; ++mf)
#pragma unroll
        for (int nf = 0; nf < 2; ++nf)
#pragma unroll
            for (int r = 0; r < 4; ++r) {
                int grow = bm + wr_ * 64 + mf * 16 + l4 * 4 + r;
                int col = bn + wc_ * 32 + nf * 16 + l15;
                PQ[(size_t)grow * 1024 + col] = (bf16)acc[mf][nf][r];
            }
}

// ---------------------------------------------------------------------------
// FUSED (R19/R21 proven, verbatim): edge split-accum elu + GLL-staged GEMM
// phases with counted vmcnt waits. Grid 256, 1024 threads (16 waves).
// XCD-bijective swizzle. LDS map (102400 B): identical to R13/R18/R19.
// ---------------------------------------------------------------------------
__global__ __launch_bounds__(1024) void fused_kernel(
    const bf16* __restrict__ PQ, const float* __restrict__ edges,
    const float* __restrict__ b1,
    const bf16* __restrict__ W2t, const float* __restrict__ ed_b2,
    const bf16* __restrict__ Wg,
    const bf16* __restrict__ f1t, const float* __restrict__ f1_b,
    const bf16* __restrict__ f2t, const float* __restrict__ f2_b,
    const float* __restrict__ f3_w, const float* __restrict__ f3_b,
    const float* __restrict__ inputs, const float* __restrict__ hidden,
    const float* __restrict__ irw, const float* __restrict__ irb,
    const float* __restrict__ iiw, const float* __restrict__ iib,
    const float* __restrict__ inw, const float* __restrict__ inb,
    float* __restrict__ NH, float* __restrict__ pred)
{
    __shared__ __align__(1024) char smem[102400];
    char* qs   = smem;
    char* sl   = smem + 65536;
    float* f3s = (float*)(smem + 65536);   // alias sl (after ph2)
    char* h1l  = smem + 73728;             // alias sl upper half (after ph2)
    char* aggl = smem + 81920;
    char* h2l  = smem + 81920;             // alias aggl (after ph3)
    char* nhl  = smem + 90112;
    float (*wls)[16] = (float(*)[16])(smem + 98304);

    const int tid = threadIdx.x;
    const int wave = tid >> 6, lane = tid & 63;
    const int l15 = lane & 15, l4 = lane >> 4;
    const int srow = lane >> 3;
    const int scol = ((lane & 7) ^ (lane >> 3)) * 8;
    // XCD-bijective swizzle: all 4 quarters of a batch on one XCD
    const int vb = (blockIdx.x & 7) * 32 + (blockIdx.x >> 3);
    const int b = vb >> 2, d0 = (vb & 3) * 16;
    const bf16* Pb = PQ + (size_t)(b * 64) * 1024;
    char* mybuf = qs + wave * 4096;        // per-wave B double-buffer (2x2KB)
    const int n0 = wave * 16;              // wave's 16 output columns

    auto stageB = [&](const bf16* Wt, int Krow, int bufi, int kt) {
        char* d = mybuf + bufi * 2048;
#pragma unroll
        for (int s = 0; s < 2; ++s)
            GLL(Wt + (size_t)(n0 + s * 8 + srow) * Krow + kt * 64 + scol,
                d + s * 1024 + lane * 16);
    };

    // ---- phase 0: stage Q (GLL, per-lane src), wls (w*log2e), p2, bb ----
#pragma unroll
    for (int si = 0; si < 4; ++si) {
        int row = wave * 4 + si;
        GLL(Pb + (size_t)row * 1024 + 512 + lane * 8, qs + row * 1024 + lane * 16);
    }
    {
        int src = tid >> 4, dc = tid & 15, d = d0 + dc;
        float w = 0.f;
        if (src != d) {
            int e = src * 63 + (d < src ? d : d - 1);
            float2 ev = ((const float2*)edges)[e];
            w = fmaxf(ev.x, ev.y) * LOG2E;
        }
        wls[src][dc] = w;
    }
    const int c = tid & 255, hh = tid >> 8;   // hh in [0,4): 4-dst group
    f32x2 p2[4];
#pragma unroll
    for (int dd = 0; dd < 4; ++dd)
        p2[dd] = unpk(*(const unsigned int*)(Pb + (size_t)(d0 + hh * 4 + dd) * 1024 + 2 * c));
    float2 bbl = *(const float2*)(b1 + 2 * c);
    f32x2 bb;  bb.x = bbl.x;  bb.y = bbl.y;
    f32x2 bb2; bb2.x = bb.x * LOG2E; bb2.y = bb.y * LOG2E;
    __syncthreads();

    // ---- phase 1: edge elu-sum, split accumulators (exact identity) ----
    {
        f32x2 accP[4], accE[4];
#pragma unroll
        for (int dd = 0; dd < 4; ++dd) {
            accP[dd] = (f32x2){0.f, 0.f};
            accE[dd] = (f32x2){0.f, 0.f};
        }
        const unsigned int* Qs32 = (const unsigned int*)qs;
#pragma unroll 4
        for (int src = 0; src < 64; ++src) {
            f32x2 qv = unpk(Qs32[src * 256 + c]);
            float4 wv = *(const float4*)&wls[src][hh * 4];
            float w[4] = {wv.x, wv.y, wv.z, wv.w};
#pragma unroll
            for (int dd = 0; dd < 4; ++dd) {
                f32x2 w2v; w2v.x = w[dd]; w2v.y = w[dd];
                f32x2 u = (p2[dd] + qv) * w2v + bb2;
                accP[dd].x += fmaxf(u.x, 0.f);
                accP[dd].y += fmaxf(u.y, 0.f);
                accE[dd].x += __builtin_amdgcn_exp2f(fminf(u.x, 0.f));
                accE[dd].y += __builtin_amdgcn_exp2f(fminf(u.y, 0.f));
            }
        }
        f32x2 selfc;
        selfc.x = (bb.x > 0.f) ? bb.x : (__expf(bb.x) - 1.f);
        selfc.y = (bb.y > 0.f) ? bb.y : (__expf(bb.y) - 1.f);
#pragma unroll
        for (int dd = 0; dd < 4; ++dd) {
            int row = hh * 4 + dd;
            bf16x2 st;
            st[0] = (bf16)(LN2 * accP[dd].x + accE[dd].x - 64.f - selfc.x);
            st[1] = (bf16)(LN2 * accP[dd].y + accE[dd].y - 64.f - selfc.y);
            *(bf16x2*)(sl + ((row * 1024 + 4 * c) ^ ((row & 7) << 4))) = st;
        }
    }
    __syncthreads();   // Q dead -> qs becomes per-wave B buffers

    // ---- phase 2: agg = S @ W2 / 63 + b2  (K=512, 8 staged k-steps) ----
    {
        f32x4 a1 = (f32x4){0.f, 0.f, 0.f, 0.f};
        stageB(W2t, 512, 0, 0);
#pragma unroll
        for (int kt = 0; kt < 8; ++kt) {
            if (kt < 7) { stageB(W2t, 512, (kt + 1) & 1, kt + 1); WAITVM2; }
            else { WAITVM0; }
            const char* bbuf = mybuf + (kt & 1) * 2048;
#pragma unroll
            for (int kk = 0; kk < 2; ++kk) {
                bf16x8 af = frag1024(sl, l15, kt * 128 + kk * 64 + l4 * 8);
                a1 = MFMA(af, frag128(bbuf, l15, kk * 64 + l4 * 8), a1);
            }
        }
        int col = n0 + l15;
        float eb = ed_b2[col];
#pragma unroll
        for (int r = 0; r < 4; ++r)
            st512(aggl, l4 * 4 + r, col, (bf16)(a1[r] * (1.f / 63.f) + eb));
    }
    __syncthreads();   // sl dead -> f3s/h1l regions usable

    for (int i = tid; i < 2048; i += 1024) f3s[i] = f3_w[i];

    // ---- phase 3: gates (3 x K=256, 12 staged steps) + GRU epilogue ----
    {
        f32x4 a2[3];
#pragma unroll
        for (int g = 0; g < 3; ++g) a2[g] = (f32x4){0.f, 0.f, 0.f, 0.f};
        stageB(Wg, 256, 0, 0);
#pragma unroll
        for (int st_ = 0; st_ < 12; ++st_) {
            const int g = st_ >> 2, kt = st_ & 3;
            if (st_ < 11) {
                const int nx = st_ + 1;
                stageB(Wg + (size_t)(nx >> 2) * 65536, 256, nx & 1, nx & 3);
                WAITVM2;
            } else { WAITVM0; }
            const char* bbuf = mybuf + (st_ & 1) * 2048;
#pragma unroll
            for (int kk = 0; kk < 2; ++kk) {
                bf16x8 af = frag512(aggl, l15, kt * 128 + kk * 64 + l4 * 8);
                a2[g] = MFMA(af, frag128(bbuf, l15, kk * 64 + l4 * 8), a2[g]);
            }
        }
        const int col = n0 + l15;
        float w8r[8], w8i[8], w8n[8];
#pragma unroll
        for (int f = 0; f < 8; ++f) {
            w8r[f] = irw[f * 256 + col];
            w8i[f] = iiw[f * 256 + col];
            w8n[f] = inw[f * 256 + col];
        }
        const float xr0 = irb[col], xi0 = iib[col], xn0 = inb[col];
#pragma unroll
        for (int r = 0; r < 4; ++r) {
            const int lrow = l4 * 4 + r;
            const int grow = b * 64 + d0 + lrow;
            const float* inp = inputs + (size_t)grow * 8;
            float xr = xr0, xi = xi0, xn = xn0;
#pragma unroll
            for (int f = 0; f < 8; ++f) {
                float x = inp[f];
                xr += x * w8r[f]; xi += x * w8i[f]; xn += x * w8n[f];
            }
            float aR = a2[0][r];
            float aI = a2[1][r];
            float aN = a2[2][r];
            float rg = __builtin_amdgcn_rcpf(1.f + __expf(-(xr + aR)));
            float ig = __builtin_amdgcn_rcpf(1.f + __expf(-(xi + aI)));
            float tz = xn + rg * aN;
            tz = fminf(fmaxf(tz, -15.f), 15.f);
            float e2x = __expf(2.f * tz);
            float nn = (e2x - 1.f) * __builtin_amdgcn_rcpf(e2x + 1.f);
            size_t o = (size_t)grow * 256 + col;
            float nh = (1.f - ig) * nn + ig * hidden[o];
            NH[o] = nh;
            st512(nhl, lrow, col, (bf16)nh);
        }
    }
    __syncthreads();   // aggl dead -> h2l region usable

    // ---- phase 4: H1 = relu(NH @ f1 + b)  (K=256, 4 staged steps) ----
    {
        f32x4 a1 = (f32x4){0.f, 0.f, 0.f, 0.f};
        stageB(f1t, 256, 0, 0);
#pragma unroll
        for (int kt = 0; kt < 4; ++kt) {
            if (kt < 3) { stageB(f1t, 256, (kt + 1) & 1, kt + 1); WAITVM2; }
            else { WAITVM0; }
            const char* bbuf = mybuf + (kt & 1) * 2048;
#pragma unroll
            for (int kk = 0; kk < 2; ++kk) {
                bf16x8 af = frag512(nhl, l15, kt * 128 + kk * 64 + l4 * 8);
                a1 = MFMA(af, frag128(bbuf, l15, kk * 64 + l4 * 8), a1);
            }
        }
        int col = n0 + l15;
        float bv = f1_b[col];
#pragma unroll
        for (int r = 0; r < 4; ++r)
            st512(h1l, l4 * 4 + r, col, (bf16)fmaxf(a1[r] + bv, 0.f));
    }
    __syncthreads();

    // ---- phase 5: H2 = relu(H1 @ f2 + b)  (K=256, 4 staged steps) ----
    {
        f32x4 a1 = (f32x4){0.f, 0.f, 0.f, 0.f};
        stageB(f2t, 256, 0, 0);
#pragma unroll
        for (int kt = 0; kt < 4; ++kt) {
            if (kt < 3) { stageB(f2t, 256, (kt + 1) & 1, kt + 1); WAITVM2; }
            else { WAITVM0; }
            const char* bbuf = mybuf + (kt & 1) * 2048;
#pragma unroll
            for (int kk = 0; kk < 2; ++kk) {
                bf16x8 af = frag512(h1l, l15, kt * 128 + kk * 64 + l4 * 8);
                a1 = MFMA(af, frag128(bbuf, l15, kk * 64 + l4 * 8), a1);
            }
        }
        int col = n0 + l15;
        float bv = f2_b[col];
#pragma unroll
        for (int r = 0; r < 4; ++r)
            st512(h2l, l4 * 4 + r, col, (bf16)fmaxf(a1[r] + bv, 0.f));
    }
    __syncthreads();

    // ---- phase 6: pred = inputs + H2 @ f3 + b ----
    if (tid < 128) {
        const int row = tid >> 3, f = tid & 7;
        const int sw = (row & 7) << 4;
        float a = f3_b[f];
        for (int k0 = 0; k0 < 256; k0 += 8) {
            bf16x8 h8 = *(const bf16x8*)(h2l + ((row * 512 + k0 * 2) ^ sw));
#pragma unroll
            for (int j = 0; j < 8; ++j)
                a += (float)h8[j] * f3s[(k0 + j) * 8 + f];
        }
        int gi = (b * 64 + d0 + row) * 8 + f;
        pred[gi] = inputs[gi] + a;
    }
}

// ---------------------------------------------------------------------------
extern "C" void kernel_launch(void* const* d_in, const int* in_sizes, int n_in,
                              void* d_out, int out_size, void* d_ws, size_t ws_size,
                              hipStream_t stream) {
    const float* inputs = (const float*)d_in[0];
    const float* hidden = (const float*)d_in[1];
    const float* edges  = (const float*)d_in[2];
    const float* ed_w1 = (const float*)d_in[4];
    const float* ed_b1 = (const float*)d_in[5];
    const float* ed_w2 = (const float*)d_in[6];
    const float* ed_b2 = (const float*)d_in[7];
    const float* wr = (const float*)d_in[8];
    const float* wi = (const float*)d_in[9];
    const float* wh = (const float*)d_in[10];
    const float* ir_w = (const float*)d_in[11];
    const float* ir_b = (const float*)d_in[12];
    const float* ii_w = (const float*)d_in[13];
    const float* ii_b = (const float*)d_in[14];
    const float* in_w = (const float*)d_in[15];
    const float* in_b = (const float*)d_in[16];
    const float* f1_w = (const float*)d_in[17];
    const float* f1_b = (const float*)d_in[18];
    const float* f2_w = (const float*)d_in[19];
    const float* f2_b = (const float*)d_in[20];
    const float* f3_w = (const float*)d_in[21];
    const float* f3_b = (const float*)d_in[22];

    float* out = (float*)d_out;
    float* pred = out;
    float* NH = out + (size_t)BB * NN * FF;

    bf16* bws = (bf16*)d_ws;
    bf16* PQ   = bws;              // 4096*1024
    bf16* W2t  = bws + 4194304;    // 256*512
    bf16* Wg   = bws + 4325376;    // 3*256*256
    bf16* f1t  = bws + 4521984;    // 256*256
    bf16* f2t  = bws + 4587520;    // 256*256

    g1pack_kernel<<<dim3(16, 39), dim3(256), 0, stream>>>(
        hidden, ed_w1, ed_w2, wr, wi, wh, f1_w, f2_w,
        PQ, W2t, Wg, f1t, f2t);

    fused_kernel<<<dim3(256), dim3(1024), 0, stream>>>(
        PQ, edges, ed_b1, W2t, ed_b2, Wg, f1t, f1_b, f2t, f2_b,
        f3_w, f3_b, inputs, hidden,
        ir_w, ir_b, ii_w, ii_b, in_w, in_b, NH, pred);
}

// Round 23
// 60.487 us; speedup vs baseline: 1.3840x; 1.0008x over previous
//
#include <hip/hip_runtime.h>
#include <hip/hip_bf16.h>
#include <math.h>

#define BB 64
#define NN 64
#define HH 256
#define FF 8

typedef __bf16 bf16;
typedef bf16 bf16x2 __attribute__((ext_vector_type(2)));
typedef bf16 bf16x4 __attribute__((ext_vector_type(4)));
typedef bf16 bf16x8 __attribute__((ext_vector_type(8)));
typedef float f32x2 __attribute__((ext_vector_type(2)));
typedef float f32x4 __attribute__((ext_vector_type(4)));

// async global->LDS, 16B per lane; LDS dest = uniform base + lane*16,
// global src must be PER-LANE (carry the lane offset explicitly!)
#define GLL(g, l) __builtin_amdgcn_global_load_lds( \
    (const __attribute__((address_space(1))) void*)(g), \
    (__attribute__((address_space(3))) void*)(l), 16, 0, 0)

#define MFMA(a, b, c) __builtin_amdgcn_mfma_f32_16x16x32_bf16(a, b, c, 0, 0, 0)

// counted waits for per-wave GLL staging ("memory" clobber orders mem ops)
#define WAITVM2 asm volatile("s_waitcnt vmcnt(2)" ::: "memory")
#define WAITVM0 asm volatile("s_waitcnt vmcnt(0)" ::: "memory")

#define LOG2E 1.44269504f
#define LN2   0.69314718f

__device__ __forceinline__ f32x2 unpk(unsigned int u) {
    union { unsigned int i; float f; } a, b;
    a.i = (u & 0xffffu) << 16;
    b.i = u & 0xffff0000u;
    f32x2 r; r.x = a.f; r.y = b.f; return r;
}

// fragment from swizzled LDS tile with 128-B rows
__device__ __forceinline__ bf16x8 frag128(const char* base, int row, int cbyte) {
    const int sw = (row & 7) << 4;
    const int a = row * 128 + cbyte;
    bf16x4 lo = *(const bf16x4*)(base + (a ^ sw));
    bf16x4 hi = *(const bf16x4*)(base + ((a + 32) ^ sw));
    return __builtin_shufflevector(lo, hi, 0, 1, 2, 3, 4, 5, 6, 7);
}

// fragment from swizzled LDS tile with 512-B rows
__device__ __forceinline__ bf16x8 frag512(const char* base, int row, int cbyte) {
    const int sw = (row & 7) << 4;
    const int a = row * 512 + cbyte;
    bf16x4 lo = *(const bf16x4*)(base + (a ^ sw));
    bf16x4 hi = *(const bf16x4*)(base + ((a + 32) ^ sw));
    return __builtin_shufflevector(lo, hi, 0, 1, 2, 3, 4, 5, 6, 7);
}

// fragment from swizzled LDS tile with 1024-B rows
__device__ __forceinline__ bf16x8 frag1024(const char* base, int row, int cbyte) {
    const int sw = (row & 7) << 4;
    const int a = row * 1024 + cbyte;
    bf16x4 lo = *(const bf16x4*)(base + (a ^ sw));
    bf16x4 hi = *(const bf16x4*)(base + ((a + 32) ^ sw));
    return __builtin_shufflevector(lo, hi, 0, 1, 2, 3, 4, 5, 6, 7);
}

__device__ __forceinline__ void st512(char* base, int row, int col, bf16 v) {
    *(bf16*)(base + ((row * 512 + col * 2) ^ ((row & 7) << 4))) = v;
}

// ---------------------------------------------------------------------------
// G1 + pack, one dispatch (R22 proven, verbatim). Grid (16, 39).
// ---------------------------------------------------------------------------
__global__ __launch_bounds__(256) void g1pack_kernel(
    const float* __restrict__ hidden, const float* __restrict__ ed_w1,
    const float* __restrict__ ed_w2,
    const float* __restrict__ wr, const float* __restrict__ wi,
    const float* __restrict__ wh,
    const float* __restrict__ f1_w, const float* __restrict__ f2_w,
    bf16* __restrict__ PQ, bf16* __restrict__ W2t, bf16* __restrict__ Wg,
    bf16* __restrict__ f1t, bf16* __restrict__ f2t)
{
    __shared__ __align__(1024) char smem[65536];
    const int tid = threadIdx.x;

    if (blockIdx.y >= 32) {
        const int t = (blockIdx.y - 32) * 16 + blockIdx.x;
        const float* src; bf16* dst; int R, C, tile;
        if (t < 32) { src = ed_w2; dst = W2t; R = 512; C = 256; tile = t; }
        else {
            int m = (t - 32) >> 4; tile = (t - 32) & 15; R = 256; C = 256;
            const float* ss[5] = {wr, wi, wh, f1_w, f2_w};
            bf16* dd[5] = {Wg, Wg + 65536, Wg + 131072, f1t, f2t};
            src = ss[m]; dst = dd[m];
        }
        const int tc = C >> 6;
        const int k0 = (tile / tc) * 64, n0 = (tile % tc) * 64;
        float (*ls)[65] = (float(*)[65])smem;
        {
            int rr = tid >> 2, cc = (tid & 3) * 16;
            const float* sp = src + (size_t)(k0 + rr) * C + n0 + cc;
#pragma unroll
            for (int j = 0; j < 16; j += 4) {
                float4 v = *(const float4*)(sp + j);
                ls[rr][cc + j] = v.x; ls[rr][cc + j + 1] = v.y;
                ls[rr][cc + j + 2] = v.z; ls[rr][cc + j + 3] = v.w;
            }
        }
        __syncthreads();
        {
            int n = tid >> 2, kc = (tid & 3) * 16;
            bf16x8 o0, o1;
#pragma unroll
            for (int j = 0; j < 8; ++j) o0[j] = (bf16)ls[kc + j][n];
#pragma unroll
            for (int j = 0; j < 8; ++j) o1[j] = (bf16)ls[kc + 8 + j][n];
            bf16* dp = dst + (size_t)(n0 + n) * R + k0 + kc;
            *(bf16x8*)dp = o0;
            *(bf16x8*)(dp + 8) = o1;
        }
        return;
    }

    // ---- G1 branch: 128-row tile (R22 proven) ----
    char* Bs = smem;
    char* pool = smem + 32768;
    const int wave = tid >> 6, lane = tid & 63;
    const int wr_ = wave >> 1, wc_ = wave & 1;
    const int l15 = lane & 15, l4 = lane >> 4;
    const int bm = blockIdx.y * 128, bn = blockIdx.x * 64;
    const int roff = (bn >= 512) ? 256 : 0;
    const int ncol = bn & 511;

    {
        float (*ls)[65] = (float(*)[65])pool;
#pragma unroll
        for (int kt = 0; kt < 4; ++kt) {
            {
                int rr = tid >> 2, cc = (tid & 3) * 16;
                const float* sp = ed_w1 + (size_t)(kt * 64 + roff + rr) * 512 + ncol + cc;
#pragma unroll
                for (int j = 0; j < 16; j += 4) {
                    float4 v = *(const float4*)(sp + j);
                    ls[rr][cc + j] = v.x; ls[rr][cc + j + 1] = v.y;
                    ls[rr][cc + j + 2] = v.z; ls[rr][cc + j + 3] = v.w;
                }
            }
            __syncthreads();
            {
                int n = tid >> 2, kc = (tid & 3) * 16;
                bf16x8 o0, o1;
#pragma unroll
                for (int j = 0; j < 8; ++j) o0[j] = (bf16)ls[kc + j][n];
#pragma unroll
                for (int j = 0; j < 8; ++j) o1[j] = (bf16)ls[kc + 8 + j][n];
                int cb0 = kt * 8 + (kc >> 3);
                char* rowp = Bs + n * 512;
                *(bf16x8*)(rowp + ((cb0 ^ (n & 7)) * 16)) = o0;
                *(bf16x8*)(rowp + (((cb0 + 1) ^ (n & 7)) * 16)) = o1;
            }
            __syncthreads();
        }
    }

    f32x4 acc[4][2];
#pragma unroll
    for (int mf = 0; mf < 4; ++mf)
#pragma unroll
        for (int nf = 0; nf < 2; ++nf)
            acc[mf][nf] = (f32x4){0.f, 0.f, 0.f, 0.f};

    auto stageA = [&](int buf, int kt) {
        char* Ab = pool + buf * 16384;
#pragma unroll
        for (int a = 0; a < 4; ++a) {
            int idx = a * 256 + tid;
            int row = idx >> 3, cb = idx & 7;
            const float* gp = hidden + (size_t)(bm + row) * 256 + kt * 64 + cb * 8;
            float4 v0 = *(const float4*)gp;
            float4 v1 = *(const float4*)(gp + 4);
            bf16x8 o;
            o[0] = (bf16)v0.x; o[1] = (bf16)v0.y; o[2] = (bf16)v0.z; o[3] = (bf16)v0.w;
            o[4] = (bf16)v1.x; o[5] = (bf16)v1.y; o[6] = (bf16)v1.z; o[7] = (bf16)v1.w;
            *(bf16x8*)(Ab + row * 128 + ((cb ^ (row & 7)) * 16)) = o;
        }
    };

    auto computeT = [&](int buf, int kt) {
        char* Ab = pool + buf * 16384;
#pragma unroll
        for (int kk = 0; kk < 2; ++kk) {
            bf16x8 af[4];
#pragma unroll
            for (int mf = 0; mf < 4; ++mf)
                af[mf] = frag128(Ab, wr_ * 64 + mf * 16 + l15, kk * 64 + l4 * 8);
#pragma unroll
            for (int nf = 0; nf < 2; ++nf) {
                bf16x8 bfr = frag512(Bs, wc_ * 32 + nf * 16 + l15,
                                     kt * 128 + kk * 64 + l4 * 8);
#pragma unroll
                for (int mf = 0; mf < 4; ++mf)
                    acc[mf][nf] = MFMA(af[mf], bfr, acc[mf][nf]);
            }
        }
    };

    stageA(0, 0);
    __syncthreads();
#pragma unroll
    for (int t = 0; t < 4; ++t) {
        if (t < 3) stageA((t + 1) & 1, t + 1);
        computeT(t & 1, t);
        __syncthreads();
    }

#pragma unroll
    for (int mf = 0; mf < 4; ++mf)
#pragma unroll
        for (int nf = 0; nf < 2; ++nf)
#pragma unroll
            for (int r = 0; r < 4; ++r) {
                int grow = bm + wr_ * 64 + mf * 16 + l4 * 4 + r;
                int col = bn + wc_ * 32 + nf * 16 + l15;
                PQ[(size_t)grow * 1024 + col] = (bf16)acc[mf][nf][r];
            }
}

// ---------------------------------------------------------------------------
// FUSED (R19/R21 base; R23: edge inner loop uses packed f32x2 max/min/add
// so clang emits v_pk_* — per-component results bitwise identical).
// Grid 256, 1024 threads (16 waves). XCD-bijective swizzle.
// LDS map (102400 B): identical to R13/R18/R19.
// ---------------------------------------------------------------------------
__global__ __launch_bounds__(1024) void fused_kernel(
    const bf16* __restrict__ PQ, const float* __restrict__ edges,
    const float* __restrict__ b1,
    const bf16* __restrict__ W2t, const float* __restrict__ ed_b2,
    const bf16* __restrict__ Wg,
    const bf16* __restrict__ f1t, const float* __restrict__ f1_b,
    const bf16* __restrict__ f2t, const float* __restrict__ f2_b,
    const float* __restrict__ f3_w, const float* __restrict__ f3_b,
    const float* __restrict__ inputs, const float* __restrict__ hidden,
    const float* __restrict__ irw, const float* __restrict__ irb,
    const float* __restrict__ iiw, const float* __restrict__ iib,
    const float* __restrict__ inw, const float* __restrict__ inb,
    float* __restrict__ NH, float* __restrict__ pred)
{
    __shared__ __align__(1024) char smem[102400];
    char* qs   = smem;
    char* sl   = smem + 65536;
    float* f3s = (float*)(smem + 65536);   // alias sl (after ph2)
    char* h1l  = smem + 73728;             // alias sl upper half (after ph2)
    char* aggl = smem + 81920;
    char* h2l  = smem + 81920;             // alias aggl (after ph3)
    char* nhl  = smem + 90112;
    float (*wls)[16] = (float(*)[16])(smem + 98304);

    const int tid = threadIdx.x;
    const int wave = tid >> 6, lane = tid & 63;
    const int l15 = lane & 15, l4 = lane >> 4;
    const int srow = lane >> 3;
    const int scol = ((lane & 7) ^ (lane >> 3)) * 8;
    // XCD-bijective swizzle: all 4 quarters of a batch on one XCD
    const int vb = (blockIdx.x & 7) * 32 + (blockIdx.x >> 3);
    const int b = vb >> 2, d0 = (vb & 3) * 16;
    const bf16* Pb = PQ + (size_t)(b * 64) * 1024;
    char* mybuf = qs + wave * 4096;        // per-wave B double-buffer (2x2KB)
    const int n0 = wave * 16;              // wave's 16 output columns

    auto stageB = [&](const bf16* Wt, int Krow, int bufi, int kt) {
        char* d = mybuf + bufi * 2048;
#pragma unroll
        for (int s = 0; s < 2; ++s)
            GLL(Wt + (size_t)(n0 + s * 8 + srow) * Krow + kt * 64 + scol,
                d + s * 1024 + lane * 16);
    };

    // ---- phase 0: stage Q (GLL, per-lane src), wls (w*log2e), p2, bb ----
#pragma unroll
    for (int si = 0; si < 4; ++si) {
        int row = wave * 4 + si;
        GLL(Pb + (size_t)row * 1024 + 512 + lane * 8, qs + row * 1024 + lane * 16);
    }
    {
        int src = tid >> 4, dc = tid & 15, d = d0 + dc;
        float w = 0.f;
        if (src != d) {
            int e = src * 63 + (d < src ? d : d - 1);
            float2 ev = ((const float2*)edges)[e];
            w = fmaxf(ev.x, ev.y) * LOG2E;
        }
        wls[src][dc] = w;
    }
    const int c = tid & 255, hh = tid >> 8;   // hh in [0,4): 4-dst group
    f32x2 p2[4];
#pragma unroll
    for (int dd = 0; dd < 4; ++dd)
        p2[dd] = unpk(*(const unsigned int*)(Pb + (size_t)(d0 + hh * 4 + dd) * 1024 + 2 * c));
    float2 bbl = *(const float2*)(b1 + 2 * c);
    f32x2 bb;  bb.x = bbl.x;  bb.y = bbl.y;
    f32x2 bb2; bb2.x = bb.x * LOG2E; bb2.y = bb.y * LOG2E;
    __syncthreads();

    // ---- phase 1: edge elu-sum, split accumulators (packed VALU form) ----
    {
        const f32x2 zero2 = (f32x2){0.f, 0.f};
        f32x2 accP[4], accE[4];
#pragma unroll
        for (int dd = 0; dd < 4; ++dd) {
            accP[dd] = zero2;
            accE[dd] = zero2;
        }
        const unsigned int* Qs32 = (const unsigned int*)qs;
#pragma unroll 4
        for (int src = 0; src < 64; ++src) {
            f32x2 qv = unpk(Qs32[src * 256 + c]);
            float4 wv = *(const float4*)&wls[src][hh * 4];
            float w[4] = {wv.x, wv.y, wv.z, wv.w};
#pragma unroll
            for (int dd = 0; dd < 4; ++dd) {
                f32x2 w2v; w2v.x = w[dd]; w2v.y = w[dd];
                f32x2 u = (p2[dd] + qv) * w2v + bb2;
                // packed max/min/add (v_pk_*); exp2 stays scalar transcendental
                accP[dd] += __builtin_elementwise_max(u, zero2);
                f32x2 um = __builtin_elementwise_min(u, zero2);
                f32x2 ev;
                ev.x = __builtin_amdgcn_exp2f(um.x);
                ev.y = __builtin_amdgcn_exp2f(um.y);
                accE[dd] += ev;
            }
        }
        f32x2 selfc;
        selfc.x = (bb.x > 0.f) ? bb.x : (__expf(bb.x) - 1.f);
        selfc.y = (bb.y > 0.f) ? bb.y : (__expf(bb.y) - 1.f);
#pragma unroll
        for (int dd = 0; dd < 4; ++dd) {
            int row = hh * 4 + dd;
            bf16x2 st;
            st[0] = (bf16)(LN2 * accP[dd].x + accE[dd].x - 64.f - selfc.x);
            st[1] = (bf16)(LN2 * accP[dd].y + accE[dd].y - 64.f - selfc.y);
            *(bf16x2*)(sl + ((row * 1024 + 4 * c) ^ ((row & 7) << 4))) = st;
        }
    }
    __syncthreads();   // Q dead -> qs becomes per-wave B buffers

    // ---- phase 2: agg = S @ W2 / 63 + b2  (K=512, 8 staged k-steps) ----
    {
        f32x4 a1 = (f32x4){0.f, 0.f, 0.f, 0.f};
        stageB(W2t, 512, 0, 0);
#pragma unroll
        for (int kt = 0; kt < 8; ++kt) {
            if (kt < 7) { stageB(W2t, 512, (kt + 1) & 1, kt + 1); WAITVM2; }
            else { WAITVM0; }
            const char* bbuf = mybuf + (kt & 1) * 2048;
#pragma unroll
            for (int kk = 0; kk < 2; ++kk) {
                bf16x8 af = frag1024(sl, l15, kt * 128 + kk * 64 + l4 * 8);
                a1 = MFMA(af, frag128(bbuf, l15, kk * 64 + l4 * 8), a1);
            }
        }
        int col = n0 + l15;
        float eb = ed_b2[col];
#pragma unroll
        for (int r = 0; r < 4; ++r)
            st512(aggl, l4 * 4 + r, col, (bf16)(a1[r] * (1.f / 63.f) + eb));
    }
    __syncthreads();   // sl dead -> f3s/h1l regions usable

    for (int i = tid; i < 2048; i += 1024) f3s[i] = f3_w[i];

    // ---- phase 3: gates (3 x K=256, 12 staged steps) + GRU epilogue ----
    {
        f32x4 a2[3];
#pragma unroll
        for (int g = 0; g < 3; ++g) a2[g] = (f32x4){0.f, 0.f, 0.f, 0.f};
        stageB(Wg, 256, 0, 0);
#pragma unroll
        for (int st_ = 0; st_ < 12; ++st_) {
            const int g = st_ >> 2, kt = st_ & 3;
            if (st_ < 11) {
                const int nx = st_ + 1;
                stageB(Wg + (size_t)(nx >> 2) * 65536, 256, nx & 1, nx & 3);
                WAITVM2;
            } else { WAITVM0; }
            const char* bbuf = mybuf + (st_ & 1) * 2048;
#pragma unroll
            for (int kk = 0; kk < 2; ++kk) {
                bf16x8 af = frag512(aggl, l15, kt * 128 + kk * 64 + l4 * 8);
                a2[g] = MFMA(af, frag128(bbuf, l15, kk * 64 + l4 * 8), a2[g]);
            }
        }
        const int col = n0 + l15;
        float w8r[8], w8i[8], w8n[8];
#pragma unroll
        for (int f = 0; f < 8; ++f) {
            w8r[f] = irw[f * 256 + col];
            w8i[f] = iiw[f * 256 + col];
            w8n[f] = inw[f * 256 + col];
        }
        const float xr0 = irb[col], xi0 = iib[col], xn0 = inb[col];
#pragma unroll
        for (int r = 0; r < 4; ++r) {
            const int lrow = l4 * 4 + r;
            const int grow = b * 64 + d0 + lrow;
            const float* inp = inputs + (size_t)grow * 8;
            float xr = xr0, xi = xi0, xn = xn0;
#pragma unroll
            for (int f = 0; f < 8; ++f) {
                float x = inp[f];
                xr += x * w8r[f]; xi += x * w8i[f]; xn += x * w8n[f];
            }
            float aR = a2[0][r];
            float aI = a2[1][r];
            float aN = a2[2][r];
            float rg = __builtin_amdgcn_rcpf(1.f + __expf(-(xr + aR)));
            float ig = __builtin_amdgcn_rcpf(1.f + __expf(-(xi + aI)));
            float tz = xn + rg * aN;
            tz = fminf(fmaxf(tz, -15.f), 15.f);
            float e2x = __expf(2.f * tz);
            float nn = (e2x - 1.f) * __builtin_amdgcn_rcpf(e2x + 1.f);
            size_t o = (size_t)grow * 256 + col;
            float nh = (1.f - ig) * nn + ig * hidden[o];
            NH[o] = nh;
            st512(nhl, lrow, col, (bf16)nh);
        }
    }
    __syncthreads();   // aggl dead -> h2l region usable

    // ---- phase 4: H1 = relu(NH @ f1 + b)  (K=256, 4 staged steps) ----
    {
        f32x4 a1 = (f32x4){0.f, 0.f, 0.f, 0.f};
        stageB(f1t, 256, 0, 0);
#pragma unroll
        for (int kt = 0; kt < 4; ++kt) {
            if (kt < 3) { stageB(f1t, 256, (kt + 1) & 1, kt + 1); WAITVM2; }
            else { WAITVM0; }
            const char* bbuf = mybuf + (kt & 1) * 2048;
#pragma unroll
            for (int kk = 0; kk < 2; ++kk) {
                bf16x8 af = frag512(nhl, l15, kt * 128 + kk * 64 + l4 * 8);
                a1 = MFMA(af, frag128(bbuf, l15, kk * 64 + l4 * 8), a1);
            }
        }
        int col = n0 + l15;
        float bv = f1_b[col];
#pragma unroll
        for (int r = 0; r < 4; ++r)
            st512(h1l, l4 * 4 + r, col, (bf16)fmaxf(a1[r] + bv, 0.f));
    }
    __syncthreads();

    // ---- phase 5: H2 = relu(H1 @ f2 + b)  (K=256, 4 staged steps) ----
    {
        f32x4 a1 = (f32x4){0.f, 0.f, 0.f, 0.f};
        stageB(f2t, 256, 0, 0);
#pragma unroll
        for (int kt = 0; kt < 4; ++kt) {
            if (kt < 3) { stageB(f2t, 256, (kt + 1) & 1, kt + 1); WAITVM2; }
            else { WAITVM0; }
            const char* bbuf = mybuf + (kt & 1) * 2048;
#pragma unroll
            for (int kk = 0; kk < 2; ++kk) {
                bf16x8 af = frag512(h1l, l15, kt * 128 + kk * 64 + l4 * 8);
                a1 = MFMA(af, frag128(bbuf, l15, kk * 64 + l4 * 8), a1);
            }
        }
        int col = n0 + l15;
        float bv = f2_b[col];
#pragma unroll
        for (int r = 0; r < 4; ++r)
            st512(h2l, l4 * 4 + r, col, (bf16)fmaxf(a1[r] + bv, 0.f));
    }
    __syncthreads();

    // ---- phase 6: pred = inputs + H2 @ f3 + b ----
    if (tid < 128) {
        const int row = tid >> 3, f = tid & 7;
        const int sw = (row & 7) << 4;
        float a = f3_b[f];
        for (int k0 = 0; k0 < 256; k0 += 8) {
            bf16x8 h8 = *(const bf16x8*)(h2l + ((row * 512 + k0 * 2) ^ sw));
#pragma unroll
            for (int j = 0; j < 8; ++j)
                a += (float)h8[j] * f3s[(k0 + j) * 8 + f];
        }
        int gi = (b * 64 + d0 + row) * 8 + f;
        pred[gi] = inputs[gi] + a;
    }
}

// ---------------------------------------------------------------------------
extern "C" void kernel_launch(void* const* d_in, const int* in_sizes, int n_in,
                              void* d_out, int out_size, void* d_ws, size_t ws_size,
                              hipStream_t stream) {
    const float* inputs = (const float*)d_in[0];
    const float* hidden = (const float*)d_in[1];
    const float* edges  = (const float*)d_in[2];
    const float* ed_w1 = (const float*)d_in[4];
    const float* ed_b1 = (const float*)d_in[5];
    const float* ed_w2 = (const float*)d_in[6];
    const float* ed_b2 = (const float*)d_in[7];
    const float* wr = (const float*)d_in[8];
    const float* wi = (const float*)d_in[9];
    const float* wh = (const float*)d_in[10];
    const float* ir_w = (const float*)d_in[11];
    const float* ir_b = (const float*)d_in[12];
    const float* ii_w = (const float*)d_in[13];
    const float* ii_b = (const float*)d_in[14];
    const float* in_w = (const float*)d_in[15];
    const float* in_b = (const float*)d_in[16];
    const float* f1_w = (const float*)d_in[17];
    const float* f1_b = (const float*)d_in[18];
    const float* f2_w = (const float*)d_in[19];
    const float* f2_b = (const float*)d_in[20];
    const float* f3_w = (const float*)d_in[21];
    const float* f3_b = (const float*)d_in[22];

    float* out = (float*)d_out;
    float* pred = out;
    float* NH = out + (size_t)BB * NN * FF;

    bf16* bws = (bf16*)d_ws;
    bf16* PQ   = bws;              // 4096*1024
    bf16* W2t  = bws + 4194304;    // 256*512
    bf16* Wg   = bws + 4325376;    // 3*256*256
    bf16* f1t  = bws + 4521984;    // 256*256
    bf16* f2t  = bws + 4587520;    // 256*256

    g1pack_kernel<<<dim3(16, 39), dim3(256), 0, stream>>>(
        hidden, ed_w1, ed_w2, wr, wi, wh, f1_w, f2_w,
        PQ, W2t, Wg, f1t, f2t);

    fused_kernel<<<dim3(256), dim3(1024), 0, stream>>>(
        PQ, edges, ed_b1, W2t, ed_b2, Wg, f1t, f1_b, f2t, f2_b,
        f3_w, f3_b, inputs, hidden,
        ir_w, ir_b, ii_w, ii_b, in_w, in_b, NH, pred);
}